// Round 17
// baseline (648.125 us; speedup 1.0000x reference)
//
#include <hip/hip_runtime.h>

#define BT (16 * 8192)
#define NB 5
#define NCELL 65536  // B * RESO^2
typedef unsigned int uint;
typedef unsigned short ushort;
typedef __attribute__((ext_vector_type(8))) _Float16 half8;
typedef __attribute__((ext_vector_type(2))) __fp16 fp16x2;
typedef __attribute__((ext_vector_type(2))) _Float16 half2v;
typedef __attribute__((ext_vector_type(4))) float f32x4;

// NOTE (r5): aT lda in dwords ≡ 4 mod 32 -> natural bank stagger; NO XOR swizzle.
// NOTE (r7): not MFMA-bound. NOTE (r9): not VALU-bound (as a whole).
// NOTE (r11): in-place 3-copy net was a cross-call hazard; r13's c3-only sorted copies
// passed and won. NOTE (r14): segmax 4-cell batching won (-77µs). NOTE (r16): segfin
// 32-cell tiles won (-24µs); resblock WRITE_SIZE 55MB vs 32MB output = scalar-ushort
// store amplification. This round: stage output tile in hT (dead after W1 pass) and
// copy to global as coalesced uint4 (16 threads/row, 256B).

// ---------- fp16 helpers ----------
__device__ __forceinline__ uint f2h2(float a, float b) {
    fp16x2 h = __builtin_amdgcn_cvt_pkrtz(a, b);
    return *(uint*)&h;
}
__device__ __forceinline__ float h2f_lo(uint u) { half2v h = *(half2v*)&u; return (float)h[0]; }
__device__ __forceinline__ float h2f_hi(uint u) { half2v h = *(half2v*)&u; return (float)h[1]; }
__device__ __forceinline__ uint pk_add(uint a, uint b) {
    uint d; asm("v_pk_add_f16 %0, %1, %2" : "=v"(d) : "v"(a), "v"(b)); return d;
}
__device__ __forceinline__ uint pk_max(uint a, uint b) {
    uint d; asm("v_pk_max_f16 %0, %1, %2" : "=v"(d) : "v"(a), "v"(b)); return d;
}

// relu on packed f16: single v_pk_max_f16 with +0 per dword
__device__ __forceinline__ half8 relu8(half8 a) {
    uint4 u = *(uint4*)&a;
    u.x = pk_max(u.x, 0u); u.y = pk_max(u.y, 0u);
    u.z = pk_max(u.z, 0u); u.w = pk_max(u.w, 0u);
    return *(half8*)&u;
}
__device__ __forceinline__ f32x4 bcast4(float x) { return (f32x4){x, x, x, x}; }
__device__ __forceinline__ f32x4 mfma16(half8 a, half8 b, f32x4 c) {
    return __builtin_amdgcn_mfma_f32_16x16x32_f16(a, b, c, 0, 0, 0);
}

// ---------- plane indices (bitwise-identical op sequence to reference) ----------
__global__ void k_idx(const float* __restrict__ p, int* __restrict__ idx,
                      int4* __restrict__ idx4) {
    int r = blockIdx.x * 256 + threadIdx.x;
    if (r >= BT) return;
    float p0 = p[3 * r + 0], p1 = p[3 * r + 1], p2 = p[3 * r + 2];
    const float DEN = (float)(1.0 + 0.1 + 1e-3);
    const float HI  = (float)(1.0 - 1e-5);
    int b = r >> 13;  // T = 8192
    float x0 = fminf(fmaxf((p0 / 8.0f) / DEN + 0.5f, 0.0f), HI);
    float x1 = fminf(fmaxf((p1 / 8.0f) / DEN + 0.5f, 0.0f), HI);
    float x2 = fminf(fmaxf((p2 / 8.0f) / DEN + 0.5f, 0.0f), HI);
    int i0 = (int)(x0 * 64.0f);
    int i1 = (int)(x1 * 64.0f);
    int i2 = (int)(x2 * 64.0f);
    int base = b << 12;
    int exz = base + i0 + (i2 << 6);
    int exy = base + i0 + (i1 << 6);
    int eyz = base + i1 + (i2 << 6);
    idx[r] = exz; idx[BT + r] = exy; idx[2 * BT + r] = eyz;
    idx4[r] = make_int4(exz, exy, eyz, 0);
}

// ---------- counting sort ----------
__global__ void k_hist(const int* __restrict__ idx, int* __restrict__ cnt) {
    int r = blockIdx.x * 256 + threadIdx.x;
    if (r >= BT) return;
    atomicAdd(cnt + idx[r], 1);
    atomicAdd(cnt + NCELL + idx[BT + r], 1);
    atomicAdd(cnt + 2 * NCELL + idx[2 * BT + r], 1);
}

__global__ __launch_bounds__(1024) void k_scan(const int* __restrict__ cnt,
                                               int* __restrict__ starts,
                                               int* __restrict__ cursor) {
    __shared__ int sc[1024];
    int pl = blockIdx.x, t = threadIdx.x;
    const int* c = cnt + pl * NCELL;
    int base = t * 64;
    int s = 0;
    for (int i = 0; i < 64; ++i) s += c[base + i];
    sc[t] = s;
    __syncthreads();
    for (int off = 1; off < 1024; off <<= 1) {
        int v = (t >= off) ? sc[t - off] : 0;
        __syncthreads();
        sc[t] += v;
        __syncthreads();
    }
    int run = sc[t] - s;
    for (int i = 0; i < 64; ++i) {
        int cell = base + i;
        starts[pl * NCELL + cell] = run;
        cursor[pl * NCELL + cell] = run;
        run += c[cell];
    }
}

// order[pl][pos] = point id; rank[pl][r] = pos (inverse permutation)
__global__ void k_scatter_order(const int* __restrict__ idx, int* __restrict__ cursor,
                                int* __restrict__ order, int* __restrict__ rank) {
    int r = blockIdx.x * 256 + threadIdx.x;
    if (r >= BT) return;
    for (int pl = 0; pl < 3; ++pl) {
        int cell = idx[pl * BT + r];
        int pos = atomicAdd(cursor + pl * NCELL + cell, 1);
        order[pl * BT + pos] = r;
        rank[pl * BT + r] = pos;
    }
}

// ---------- weight convert f32 row-major -> f16 fragment layout [K/32][128][32] ----------
__global__ void k_wconv(const float* __restrict__ W0, const float* __restrict__ W1,
                        const float* __restrict__ Ws, const float* __restrict__ Wc,
                        ushort* __restrict__ wb) {
    int mat = blockIdx.y;
    int K = (mat < 5 || (mat >= 10 && mat < 15)) ? 384 : 128;
    int e = blockIdx.x * 256 + threadIdx.x;
    if (e >= K * 128) return;
    const float* src;
    size_t doff;
    if (mat < 5)       { src = W0 + (size_t)mat * 49152;        doff = (size_t)mat * 49152; }
    else if (mat < 10) { src = W1 + (size_t)(mat - 5) * 16384;  doff = 245760 + (size_t)(mat - 5) * 16384; }
    else if (mat < 15) { src = Ws + (size_t)(mat - 10) * 49152; doff = 327680 + (size_t)(mat - 10) * 49152; }
    else               { src = Wc;                              doff = 573440; }
    int ko = e & 31, n = (e >> 5) & 127, kt = e >> 12;
    wb[doff + e] = (ushort)f2h2(src[(size_t)(kt * 32 + ko) * 128 + n], 0.0f);
}

// ---------- block-0 shortcut fold: M3 = Wp @ Ws0 (3x128), bps = bp @ Ws0 + b1 ----------
__global__ __launch_bounds__(128) void k_pfold(const float* __restrict__ Wp,
                                               const float* __restrict__ bp,
                                               const float* __restrict__ Ws0,
                                               const float* __restrict__ b1v,
                                               float* __restrict__ M3,
                                               float* __restrict__ bps) {
    int n = threadIdx.x;
    float s0 = 0.f, s1 = 0.f, s2 = 0.f, sb = b1v[n];
    for (int k = 0; k < 384; ++k) {
        float w = Ws0[(size_t)k * 128 + n];
        s0 = fmaf(Wp[k], w, s0);
        s1 = fmaf(Wp[384 + k], w, s1);
        s2 = fmaf(Wp[768 + k], w, s2);
        sb = fmaf(bp[k], w, sb);
    }
    M3[n] = s0; M3[128 + n] = s1; M3[256 + n] = s2;
    bps[n] = sb;
}

// ---------- segmented max: 4 cells per wave, batched gathers + meanvec tail ----------
__global__ __launch_bounds__(256) void k_segmax(const uint* __restrict__ netu,
                                                const int* __restrict__ starts,
                                                const int* __restrict__ cnt,
                                                const int* __restrict__ order,
                                                uint* __restrict__ segu,
                                                const float* __restrict__ meanPrev,
                                                const ushort* __restrict__ wb0,
                                                const float* __restrict__ b0v,
                                                const ushort* __restrict__ wbs,
                                                const float* __restrict__ b1v,
                                                float* __restrict__ rv0,
                                                float* __restrict__ rvS) {
    int t = threadIdx.x;
    if (blockIdx.x >= 12288) {
        __shared__ float ms[128];
        int b = blockIdx.x - 12288;
        if (t < 128) ms[t] = meanPrev[b * 128 + t];
        __syncthreads();
        if (t < 128) {
            float s0 = b0v[t], ss = b1v[t];
#pragma unroll 4
            for (int k = 0; k < 128; ++k) {
                float mv = ms[k];
                int kt = 8 + (k >> 5), ko = k & 31;
                float w0 = h2f_lo((uint)wb0[kt * 4096 + t * 32 + ko]);
                float ws = h2f_lo((uint)wbs[kt * 4096 + t * 32 + ko]);
                s0 = fmaf(fmaxf(mv, 0.0f), w0, s0);
                ss = fmaf(mv, ws, ss);
            }
            rv0[b * 128 + t] = s0;
            rvS[b * 128 + t] = ss;
        }
        return;
    }
    const int l = t & 63, wv = t >> 6;
    const int g0 = blockIdx.x * 16 + wv * 4;   // wave's first cell (4 consecutive)
    const int pl = g0 >> 16;                   // uniform per block (NCELL % 16 == 0)
    const int* ordp = order + pl * BT;

    int n[4], st[4];
#pragma unroll
    for (int c = 0; c < 4; ++c) { n[c] = cnt[g0 + c]; st[c] = starts[g0 + c]; }

    uint v[4][4];
#pragma unroll
    for (int c = 0; c < 4; ++c) {
        if (n[c] > 0) {
            const int* op = ordp + st[c];
            int nm1 = n[c] - 1;
#pragma unroll
            for (int k = 0; k < 4; ++k) {
                int kk = k < nm1 ? k : nm1;
                v[c][k] = netu[(size_t)op[kk] * 64 + l];
            }
        }
    }
#pragma unroll
    for (int c = 0; c < 4; ++c) {
        if (n[c] > 0) {
            uint m = pk_max(pk_max(v[c][0], v[c][1]), pk_max(v[c][2], v[c][3]));
            const int* op = ordp + st[c];
            int nm1 = n[c] - 1;
            for (int k = 4; k < n[c]; k += 4) {  // rare tail (n > 4)
                int k1 = k + 1 < nm1 ? k + 1 : nm1;
                int k2 = k + 2 < nm1 ? k + 2 : nm1;
                int k3 = k + 3 < nm1 ? k + 3 : nm1;
                uint a = netu[(size_t)op[k] * 64 + l];
                uint b = netu[(size_t)op[k1] * 64 + l];
                uint cc = netu[(size_t)op[k2] * 64 + l];
                uint d = netu[(size_t)op[k3] * 64 + l];
                m = pk_max(m, pk_max(pk_max(a, b), pk_max(cc, d)));
            }
            segu[(size_t)(g0 + c) * 64 + l] = m;
        }
    }
}

// ---------- fused resblock (f16 MFMA, padded LDS, rank-1 mean, rank-3 p-fold) ----------
// Output staged in hT (dead after W1 pass) then copied to global as coalesced uint4.
template <int MODE>
__global__ __launch_bounds__(512, MODE == 0 ? 6 : 8) void k_resblock(
    const float* __restrict__ p, const uint* __restrict__ netu,
    const int4* __restrict__ idx4, const ushort* __restrict__ seg,
    const float* __restrict__ rv0, const float* __restrict__ rvS,
    const float* __restrict__ Wp, const float* __restrict__ bp,
    const float* __restrict__ M3, const float* __restrict__ bps,
    const ushort* __restrict__ wb0, const float* __restrict__ b0v,
    const ushort* __restrict__ wb1, const float* __restrict__ b1v,
    const ushort* __restrict__ wbs,
    ushort* __restrict__ out, float* __restrict__ meanW) {
    constexpr int LDA = (MODE == 0) ? 392 : 264;  // ushort stride; dwords ≡ 4 mod 32
    constexpr int NKT = (MODE == 0) ? 12 : 8;
    __shared__ __align__(16) ushort aT[64 * LDA];
    __shared__ float pS[MODE == 0 ? 192 : 1];  // MODE0: 64 rows x 3 f32
    ushort* hT = aT;  // alias: reused for hidden tile, then for output staging
    const int t = threadIdx.x;  // 0..511
    const int rowBase = blockIdx.x * 64;
    const int bb = rowBase >> 13;

    if constexpr (MODE == 0) {
        if (t < 192) pS[t] = p[(size_t)rowBase * 3 + t];
        __syncthreads();
        for (int f = t; f < 3072; f += 512) {
            int row = f / 48, g = f - row * 48;
            float p0 = pS[row * 3 + 0], p1 = pS[row * 3 + 1], p2 = pS[row * 3 + 2];
            int k0 = g * 8;
            uint d[4];
#pragma unroll
            for (int w = 0; w < 4; ++w) {
                int k = k0 + 2 * w;
                float v0 = bp[k]     + p0 * Wp[k]     + p1 * Wp[384 + k]     + p2 * Wp[768 + k];
                float v1 = bp[k + 1] + p0 * Wp[k + 1] + p1 * Wp[384 + k + 1] + p2 * Wp[768 + k + 1];
                d[w] = f2h2(v0, v1);
            }
            *(uint4*)(aT + row * LDA + k0) = make_uint4(d[0], d[1], d[2], d[3]);
        }
    } else {
        const uint4* nsrc = (const uint4*)netu;
#pragma unroll
        for (int i = 0; i < 2; ++i) {  // net -> cols [0,128)
            int f = t + 512 * i;
            int row = f >> 4, cu = f & 15;
            *(uint4*)(aT + row * LDA + cu * 8) = nsrc[(size_t)(rowBase + row) * 16 + cu];
        }
#pragma unroll
        for (int i = 0; i < 2; ++i) {  // pooled (3-plane packed-f16 sum) -> cols [128,256)
            int f = t + 512 * i;
            int row = f >> 4, grp = f & 15;
            int4 cc = idx4[rowBase + row];
            uint4 A = *(const uint4*)(seg + ((size_t)cc.x) * 128 + grp * 8);
            uint4 B = *(const uint4*)(seg + ((size_t)NCELL + cc.y) * 128 + grp * 8);
            uint4 C = *(const uint4*)(seg + ((size_t)2 * NCELL + cc.z) * 128 + grp * 8);
            uint4 d;
            d.x = pk_add(pk_add(A.x, B.x), C.x);
            d.y = pk_add(pk_add(A.y, B.y), C.y);
            d.z = pk_add(pk_add(A.z, B.z), C.z);
            d.w = pk_add(pk_add(A.w, B.w), C.w);
            *(uint4*)(aT + row * LDA + 128 + grp * 8) = d;
        }
    }
    __syncthreads();

    const int l = t & 63, wid = t >> 6;  // wid 0..7
    const int n0 = wid * 16;
    const int lm = l & 15, lg = l >> 4;
    const ushort* w0 = wb0 + n0 * 32;
    const ushort* w1 = wb1 + n0 * 32;
    const ushort* ws = wbs + n0 * 32;

    f32x4 acc0[4], accS[4];
    {
        float bi;
        if constexpr (MODE == 0) bi = b0v[n0 + lm];
        else                     bi = rv0[bb * 128 + n0 + lm];
#pragma unroll
        for (int im = 0; im < 4; ++im) acc0[im] = bcast4(bi);
    }
    if constexpr (MODE == 1) {
        float si = rvS[bb * 128 + n0 + lm];
#pragma unroll
        for (int im = 0; im < 4; ++im) accS[im] = bcast4(si);
    }
#pragma unroll
    for (int kt = 0; kt < NKT; ++kt) {
        half8 b0 = *(const half8*)(w0 + kt * 4096 + lm * 32 + lg * 8);
        half8 bs;
        if constexpr (MODE == 1) bs = *(const half8*)(ws + kt * 4096 + lm * 32 + lg * 8);
#pragma unroll
        for (int im = 0; im < 4; ++im) {
            half8 a = *(const half8*)(aT + (im * 16 + lm) * LDA + kt * 32 + lg * 8);
            acc0[im] = mfma16(relu8(a), b0, acc0[im]);
            if constexpr (MODE == 1) accS[im] = mfma16(a, bs, accS[im]);
        }
    }
    if constexpr (MODE == 0) {
        int col = n0 + lm;
        float m0 = M3[col], m1 = M3[128 + col], m2 = M3[256 + col], bb2 = bps[col];
#pragma unroll
        for (int im = 0; im < 4; ++im)
#pragma unroll
            for (int j = 0; j < 4; ++j) {
                int row = im * 16 + lg * 4 + j;
                accS[im][j] = fmaf(pS[row * 3 + 0], m0,
                              fmaf(pS[row * 3 + 1], m1,
                              fmaf(pS[row * 3 + 2], m2, bb2)));
            }
    }
    __syncthreads();  // all waves done READING aT (and pS) before hT overwrites

    // h = relu(acc0) -> hT (aliases aT; stride 136, dwords 68 ≡ 4 mod 32)
#pragma unroll
    for (int im = 0; im < 4; ++im)
#pragma unroll
        for (int j = 0; j < 4; ++j) {
            int row = im * 16 + lg * 4 + j;
            hT[row * 136 + n0 + lm] = (ushort)f2h2(fmaxf(acc0[im][j], 0.0f), 0.0f);
        }
    __syncthreads();

    // accS += h @ W1
#pragma unroll
    for (int kt = 0; kt < 4; ++kt) {
        half8 b = *(const half8*)(w1 + kt * 4096 + lm * 32 + lg * 8);
#pragma unroll
        for (int im = 0; im < 4; ++im) {
            half8 a = *(const half8*)(hT + (im * 16 + lm) * 136 + kt * 32 + lg * 8);
            accS[im] = mfma16(a, b, accS[im]);
        }
    }
    __syncthreads();  // all waves done READING hT before output staging overwrites

    // stage output tile (f16) into hT, then coalesced uint4 copy to global
#pragma unroll
    for (int im = 0; im < 4; ++im)
#pragma unroll
        for (int j = 0; j < 4; ++j) {
            int row = im * 16 + lg * 4 + j;
            hT[row * 136 + n0 + lm] = (ushort)f2h2(accS[im][j], 0.0f);
        }

    // fused batch-mean (registers only; safe before the staging barrier)
    if (meanW) {
        float s = 0.0f;
#pragma unroll
        for (int im = 0; im < 4; ++im)
#pragma unroll
            for (int j = 0; j < 4; ++j) s += accS[im][j];
        s += __shfl_xor(s, 16);
        s += __shfl_xor(s, 32);
        if (l < 16) atomicAdd(meanW + bb * 128 + n0 + l, s * (1.0f / 8192.0f));
    }
    __syncthreads();

#pragma unroll
    for (int i = 0; i < 2; ++i) {  // 1024 uint4 = 64 rows x 16
        int f = t + 512 * i;
        int row = f >> 4, cu = f & 15;
        *(uint4*)(out + (size_t)(rowBase + row) * 128 + cu * 8) =
            *(const uint4*)(hT + row * 136 + cu * 8);
    }
}

// ---------- GEMM helper (k_fcc only) ----------
__device__ __forceinline__ void mfma_gemm3(const ushort* __restrict__ aLDS, int lda, int nk,
                                           const ushort* __restrict__ wb, int lm, int lg,
                                           f32x4 acc[4][2]) {
    for (int kt = 0; kt < nk; ++kt) {
        half8 b0 = *(const half8*)(wb + kt * 4096 + lm * 32 + lg * 8);
        half8 b1 = *(const half8*)(wb + kt * 4096 + (16 + lm) * 32 + lg * 8);
#pragma unroll
        for (int im = 0; im < 4; ++im) {
            half8 a = *(const half8*)(aLDS + (im * 16 + lm) * lda + kt * 32 + lg * 8);
            acc[im][0] = mfma16(a, b0, acc[im][0]);
            acc[im][1] = mfma16(a, b1, acc[im][1]);
        }
    }
}

// ---------- final projection: c3[pl][rank[pl][r]] = (net @ Wc + bc)[r], 3 sorted copies ----------
__global__ __launch_bounds__(256, 2) void k_fcc(const uint* __restrict__ netu,
                                                const int* __restrict__ rank,
                                                const ushort* __restrict__ wbc,
                                                const float* __restrict__ bc,
                                                ushort* __restrict__ c3) {
    __shared__ __align__(16) ushort aT[64 * 136];
    __shared__ int rkS[3][64];
    const int t = threadIdx.x;
    const int rowBase = blockIdx.x * 64;
    if (t < 192) {
        int pl = t >> 6, rr = t & 63;
        rkS[pl][rr] = rank[pl * BT + rowBase + rr];
    }
    const uint4* nsrc = (const uint4*)netu;
#pragma unroll
    for (int i = 0; i < 4; ++i) {
        int u = t + 256 * i;
        int row = u >> 4, cu = u & 15;
        *(uint4*)(aT + row * 136 + cu * 8) = nsrc[(size_t)(rowBase + row) * 16 + cu];
    }
    __syncthreads();
    const int l = t & 63, wid = t >> 6;
    const int n0 = wid * 32;
    const int lm = l & 15, lg = l >> 4;
    f32x4 acc[4][2];
    {
        float ci0 = bc[n0 + lm], ci1 = bc[n0 + 16 + lm];
#pragma unroll
        for (int im = 0; im < 4; ++im) { acc[im][0] = bcast4(ci0); acc[im][1] = bcast4(ci1); }
    }
    mfma_gemm3(aT, 136, 4, wbc + n0 * 32, lm, lg, acc);
#pragma unroll
    for (int im = 0; im < 4; ++im)
#pragma unroll
        for (int ic = 0; ic < 2; ++ic)
#pragma unroll
            for (int j = 0; j < 4; ++j) {
                int row = im * 16 + lg * 4 + j;
                int col = n0 + ic * 16 + lm;
                ushort v = (ushort)f2h2(acc[im][ic][j], 0.0f);
                c3[(size_t)rkS[0][row] * 128 + col] = v;
                c3[((size_t)BT + rkS[1][row]) * 128 + col] = v;
                c3[((size_t)2 * BT + rkS[2][row]) * 128 + col] = v;
            }
}

// ---------- fused segmented-sum + transpose + divide over CONTIGUOUS runs ----------
// 32 cells/block (16.6 KB LDS -> 8 blocks/CU = 100% occupancy ceiling); 6144 blocks.
__global__ __launch_bounds__(256) void k_segfin(const uint* __restrict__ c3,
                                                const int* __restrict__ starts,
                                                const int* __restrict__ cnt,
                                                float* __restrict__ out) {
    __shared__ float tile[32 * 130];  // stride 130 dwords ≡ 2 mod 32 (2-way max)
    const int t = threadIdx.x;
    const int w = t >> 6, l = t & 63;
    const int bx = blockIdx.x;
    const int pl = bx >> 11;          // 2048 blocks per plane
    const int rem = bx & 2047;
    const int b = rem >> 7;
    const int cl0 = (rem & 127) << 5;  // 32 cells per block
    const int gbase = pl * NCELL + (b << 12) + cl0;

    for (int i = 0; i < 8; ++i) {
        int cellLocal = w * 8 + i;
        int g = gbase + cellLocal;
        int n = cnt[g];
        float s0 = 0.f, s1 = 0.f;
        if (n > 0) {
            size_t rowb = (size_t)pl * BT + starts[g];  // contiguous run
            int j = 0;
            for (; j + 4 <= n; j += 4) {
                uint a = c3[(rowb + j) * 64 + l];
                uint bq = c3[(rowb + j + 1) * 64 + l];
                uint c = c3[(rowb + j + 2) * 64 + l];
                uint d = c3[(rowb + j + 3) * 64 + l];
                s0 += (h2f_lo(a) + h2f_lo(bq)) + (h2f_lo(c) + h2f_lo(d));
                s1 += (h2f_hi(a) + h2f_hi(bq)) + (h2f_hi(c) + h2f_hi(d));
            }
            int rm = n - j;
            if (rm > 0) {
                uint a = c3[(rowb + j) * 64 + l];
                uint bq = (rm > 1) ? c3[(rowb + j + 1) * 64 + l] : 0u;
                uint c = (rm > 2) ? c3[(rowb + j + 2) * 64 + l] : 0u;
                s0 += h2f_lo(a) + (h2f_lo(bq) + h2f_lo(c));
                s1 += h2f_hi(a) + (h2f_hi(bq) + h2f_hi(c));
            }
        }
        *(float2*)(tile + cellLocal * 130 + 2 * l) = make_float2(s0, s1);
    }
    __syncthreads();

    // write: thread t -> cell (t & 31), channels [(t>>5)*16, +16)
    const int cell = t & 31;
    const int ch0 = (t >> 5) * 16;
    int cn = cnt[gbase + cell];
    float inv = cn > 0 ? 1.0f / (float)cn : 0.0f;
    size_t obase = (((size_t)((pl * 16 + b) * 128)) << 12) + cl0 + cell;
#pragma unroll
    for (int j = 0; j < 16; ++j) {
        int ch = ch0 + j;
        out[obase + ((size_t)ch << 12)] = tile[cell * 130 + ch] * inv;
    }
}

// ---------- launch ----------
extern "C" void kernel_launch(void* const* d_in, const int* in_sizes, int n_in,
                              void* d_out, int out_size, void* d_ws, size_t ws_size,
                              hipStream_t stream) {
    const float* p  = (const float*)d_in[0];
    const float* Wp = (const float*)d_in[1];
    const float* bp = (const float*)d_in[2];
    const float* W0 = (const float*)d_in[3];
    const float* b0 = (const float*)d_in[4];
    const float* W1 = (const float*)d_in[5];
    const float* b1 = (const float*)d_in[6];
    const float* Ws = (const float*)d_in[7];
    const float* Wc = (const float*)d_in[8];
    const float* bc = (const float*)d_in[9];
    float* out = (float*)d_out;

    // workspace (~138 MB). seg ALIASES c3's first 48MB: seg is dead (last read by the
    // final resblock) before k_fcc writes c3 — stream-ordered, no overlap in time.
    ushort* c3     = (ushort*)d_ws;              // 3 x 16,777,216 ushorts (96 MB)
    ushort* seg    = c3;                         // alias, 25,165,824 ushorts (48 MB)
    ushort* net    = c3 + 50331648;              // 16,777,216 ushorts (32 MB)
    ushort* wb     = net + 16777216;             // 589,824 ushorts
    int*    idx    = (int*)(wb + 589824);        // 393,216 ints
    int*    order  = idx + 393216;               // 393,216
    int*    rank   = order + 393216;             // 393,216
    int*    cnt    = rank + 393216;              // 196,608
    int*    starts = cnt + 196608;               // 196,608
    int*    cursor = starts + 196608;            // 196,608
    int4*   idx4   = (int4*)(cursor + 196608);   // 131,072 int4 (2 MB)
    float*  meanB  = (float*)(idx4 + 131072);    // 4 x 2048 f32
    float*  rv0    = meanB + 4 * 2048;           // 2048
    float*  rvS    = rv0 + 2048;                 // 2048
    float*  M3     = rvS + 2048;                 // 384
    float*  bps    = M3 + 384;                   // 128

    // --- sort points by cell (loop-invariant) + weight convert + p-fold ---
    k_idx<<<512, 256, 0, stream>>>(p, idx, idx4);
    (void)hipMemsetAsync(cnt, 0, 3 * NCELL * 4, stream);
    k_hist<<<512, 256, 0, stream>>>(idx, cnt);
    k_scan<<<3, 1024, 0, stream>>>(cnt, starts, cursor);
    k_scatter_order<<<512, 256, 0, stream>>>(idx, cursor, order, rank);
    k_wconv<<<dim3(192, 16), 256, 0, stream>>>(W0, W1, Ws, Wc, wb);
    k_pfold<<<1, 128, 0, stream>>>(Wp, bp, Ws, b1, M3, bps);
    (void)hipMemsetAsync(meanB, 0, 4 * 2048 * 4, stream);

    // --- block 0 (fc_pos fused, shortcut folded), writes mean slot 0 ---
    k_resblock<0><<<2048, 512, 0, stream>>>(
        p, nullptr, nullptr, nullptr, nullptr, nullptr, Wp, bp, M3, bps,
        wb, b0, wb + 245760, b1, wb + 327680, net, meanB);

    for (int i = 1; i < NB; ++i) {
        const ushort* wb0i = wb + (size_t)i * 49152;
        const ushort* wb1i = wb + 245760 + (size_t)i * 16384;
        const ushort* wbsi = wb + 327680 + (size_t)i * 49152;
        // segmax (3 planes, 16 cells/block) + meanvec tail in one launch
        k_segmax<<<12304, 256, 0, stream>>>((const uint*)net, starts, cnt, order, (uint*)seg,
                                            meanB + (i - 1) * 2048, wb0i, b0 + i * 128,
                                            wbsi, b1 + i * 128, rv0, rvS);
        float* mw = (i < NB - 1) ? meanB + i * 2048 : nullptr;
        k_resblock<1><<<2048, 512, 0, stream>>>(
            nullptr, (const uint*)net, idx4, seg, rv0, rvS, nullptr, nullptr,
            nullptr, nullptr, wb0i, nullptr, wb1i, nullptr, wbsi, net, mw);
    }

    // --- c3 = 3 per-plane sorted copies of (net @ Wc + bc) ---
    k_fcc<<<2048, 256, 0, stream>>>((const uint*)net, rank, wb + 573440, bc, c3);

    // --- fused segmented sum + transpose + divide, contiguous runs (32-cell tiles) ---
    k_segfin<<<6144, 256, 0, stream>>>((const uint*)c3, starts, cnt, out);
}

// Round 18
// 635.965 us; speedup vs baseline: 1.0191x; 1.0191x over previous
//
#include <hip/hip_runtime.h>

#define BT (16 * 8192)
#define NB 5
#define NCELL 65536  // B * RESO^2
typedef unsigned int uint;
typedef unsigned short ushort;
typedef __attribute__((ext_vector_type(8))) _Float16 half8;
typedef __attribute__((ext_vector_type(2))) __fp16 fp16x2;
typedef __attribute__((ext_vector_type(2))) _Float16 half2v;
typedef __attribute__((ext_vector_type(4))) float f32x4;

// NOTE (r5): aT lda in dwords ≡ 4 mod 32 -> natural bank stagger; NO XOR swizzle.
// NOTE (r7): not MFMA-bound. NOTE (r9): not VALU-bound. NOTE (r11): never alias a
// buffer read and written by the SAME kernel across blocks. NOTE (r17): scalar ushort
// tile stores do NOT amplify writes (L2 write-combines) — staging was neutral, reverted.
// This round: fuse fc_c into the LAST resblock (saves 64MB round-trip + 1 dispatch);
// fused path needs seg separate from c3 -> guarded on ws_size with r16 fallback.

// ---------- fp16 helpers ----------
__device__ __forceinline__ uint f2h2(float a, float b) {
    fp16x2 h = __builtin_amdgcn_cvt_pkrtz(a, b);
    return *(uint*)&h;
}
__device__ __forceinline__ float h2f_lo(uint u) { half2v h = *(half2v*)&u; return (float)h[0]; }
__device__ __forceinline__ float h2f_hi(uint u) { half2v h = *(half2v*)&u; return (float)h[1]; }
__device__ __forceinline__ uint pk_add(uint a, uint b) {
    uint d; asm("v_pk_add_f16 %0, %1, %2" : "=v"(d) : "v"(a), "v"(b)); return d;
}
__device__ __forceinline__ uint pk_max(uint a, uint b) {
    uint d; asm("v_pk_max_f16 %0, %1, %2" : "=v"(d) : "v"(a), "v"(b)); return d;
}

// relu on packed f16: single v_pk_max_f16 with +0 per dword
__device__ __forceinline__ half8 relu8(half8 a) {
    uint4 u = *(uint4*)&a;
    u.x = pk_max(u.x, 0u); u.y = pk_max(u.y, 0u);
    u.z = pk_max(u.z, 0u); u.w = pk_max(u.w, 0u);
    return *(half8*)&u;
}
__device__ __forceinline__ f32x4 bcast4(float x) { return (f32x4){x, x, x, x}; }
__device__ __forceinline__ f32x4 mfma16(half8 a, half8 b, f32x4 c) {
    return __builtin_amdgcn_mfma_f32_16x16x32_f16(a, b, c, 0, 0, 0);
}

// ---------- plane indices (bitwise-identical op sequence to reference) ----------
__global__ void k_idx(const float* __restrict__ p, int* __restrict__ idx,
                      int4* __restrict__ idx4) {
    int r = blockIdx.x * 256 + threadIdx.x;
    if (r >= BT) return;
    float p0 = p[3 * r + 0], p1 = p[3 * r + 1], p2 = p[3 * r + 2];
    const float DEN = (float)(1.0 + 0.1 + 1e-3);
    const float HI  = (float)(1.0 - 1e-5);
    int b = r >> 13;  // T = 8192
    float x0 = fminf(fmaxf((p0 / 8.0f) / DEN + 0.5f, 0.0f), HI);
    float x1 = fminf(fmaxf((p1 / 8.0f) / DEN + 0.5f, 0.0f), HI);
    float x2 = fminf(fmaxf((p2 / 8.0f) / DEN + 0.5f, 0.0f), HI);
    int i0 = (int)(x0 * 64.0f);
    int i1 = (int)(x1 * 64.0f);
    int i2 = (int)(x2 * 64.0f);
    int base = b << 12;
    int exz = base + i0 + (i2 << 6);
    int exy = base + i0 + (i1 << 6);
    int eyz = base + i1 + (i2 << 6);
    idx[r] = exz; idx[BT + r] = exy; idx[2 * BT + r] = eyz;
    idx4[r] = make_int4(exz, exy, eyz, 0);
}

// ---------- counting sort ----------
__global__ void k_hist(const int* __restrict__ idx, int* __restrict__ cnt) {
    int r = blockIdx.x * 256 + threadIdx.x;
    if (r >= BT) return;
    atomicAdd(cnt + idx[r], 1);
    atomicAdd(cnt + NCELL + idx[BT + r], 1);
    atomicAdd(cnt + 2 * NCELL + idx[2 * BT + r], 1);
}

__global__ __launch_bounds__(1024) void k_scan(const int* __restrict__ cnt,
                                               int* __restrict__ starts,
                                               int* __restrict__ cursor) {
    __shared__ int sc[1024];
    int pl = blockIdx.x, t = threadIdx.x;
    const int* c = cnt + pl * NCELL;
    int base = t * 64;
    int s = 0;
    for (int i = 0; i < 64; ++i) s += c[base + i];
    sc[t] = s;
    __syncthreads();
    for (int off = 1; off < 1024; off <<= 1) {
        int v = (t >= off) ? sc[t - off] : 0;
        __syncthreads();
        sc[t] += v;
        __syncthreads();
    }
    int run = sc[t] - s;
    for (int i = 0; i < 64; ++i) {
        int cell = base + i;
        starts[pl * NCELL + cell] = run;
        cursor[pl * NCELL + cell] = run;
        run += c[cell];
    }
}

// order[pl][pos] = point id; rank[pl][r] = pos (inverse permutation)
__global__ void k_scatter_order(const int* __restrict__ idx, int* __restrict__ cursor,
                                int* __restrict__ order, int* __restrict__ rank) {
    int r = blockIdx.x * 256 + threadIdx.x;
    if (r >= BT) return;
    for (int pl = 0; pl < 3; ++pl) {
        int cell = idx[pl * BT + r];
        int pos = atomicAdd(cursor + pl * NCELL + cell, 1);
        order[pl * BT + pos] = r;
        rank[pl * BT + r] = pos;
    }
}

// ---------- weight convert f32 row-major -> f16 fragment layout [K/32][128][32] ----------
__global__ void k_wconv(const float* __restrict__ W0, const float* __restrict__ W1,
                        const float* __restrict__ Ws, const float* __restrict__ Wc,
                        ushort* __restrict__ wb) {
    int mat = blockIdx.y;
    int K = (mat < 5 || (mat >= 10 && mat < 15)) ? 384 : 128;
    int e = blockIdx.x * 256 + threadIdx.x;
    if (e >= K * 128) return;
    const float* src;
    size_t doff;
    if (mat < 5)       { src = W0 + (size_t)mat * 49152;        doff = (size_t)mat * 49152; }
    else if (mat < 10) { src = W1 + (size_t)(mat - 5) * 16384;  doff = 245760 + (size_t)(mat - 5) * 16384; }
    else if (mat < 15) { src = Ws + (size_t)(mat - 10) * 49152; doff = 327680 + (size_t)(mat - 10) * 49152; }
    else               { src = Wc;                              doff = 573440; }
    int ko = e & 31, n = (e >> 5) & 127, kt = e >> 12;
    wb[doff + e] = (ushort)f2h2(src[(size_t)(kt * 32 + ko) * 128 + n], 0.0f);
}

// ---------- block-0 shortcut fold: M3 = Wp @ Ws0 (3x128), bps = bp @ Ws0 + b1 ----------
__global__ __launch_bounds__(128) void k_pfold(const float* __restrict__ Wp,
                                               const float* __restrict__ bp,
                                               const float* __restrict__ Ws0,
                                               const float* __restrict__ b1v,
                                               float* __restrict__ M3,
                                               float* __restrict__ bps) {
    int n = threadIdx.x;
    float s0 = 0.f, s1 = 0.f, s2 = 0.f, sb = b1v[n];
    for (int k = 0; k < 384; ++k) {
        float w = Ws0[(size_t)k * 128 + n];
        s0 = fmaf(Wp[k], w, s0);
        s1 = fmaf(Wp[384 + k], w, s1);
        s2 = fmaf(Wp[768 + k], w, s2);
        sb = fmaf(bp[k], w, sb);
    }
    M3[n] = s0; M3[128 + n] = s1; M3[256 + n] = s2;
    bps[n] = sb;
}

// ---------- segmented max: 4 cells per wave, batched gathers + meanvec tail ----------
__global__ __launch_bounds__(256) void k_segmax(const uint* __restrict__ netu,
                                                const int* __restrict__ starts,
                                                const int* __restrict__ cnt,
                                                const int* __restrict__ order,
                                                uint* __restrict__ segu,
                                                const float* __restrict__ meanPrev,
                                                const ushort* __restrict__ wb0,
                                                const float* __restrict__ b0v,
                                                const ushort* __restrict__ wbs,
                                                const float* __restrict__ b1v,
                                                float* __restrict__ rv0,
                                                float* __restrict__ rvS) {
    int t = threadIdx.x;
    if (blockIdx.x >= 12288) {
        __shared__ float ms[128];
        int b = blockIdx.x - 12288;
        if (t < 128) ms[t] = meanPrev[b * 128 + t];
        __syncthreads();
        if (t < 128) {
            float s0 = b0v[t], ss = b1v[t];
#pragma unroll 4
            for (int k = 0; k < 128; ++k) {
                float mv = ms[k];
                int kt = 8 + (k >> 5), ko = k & 31;
                float w0 = h2f_lo((uint)wb0[kt * 4096 + t * 32 + ko]);
                float ws = h2f_lo((uint)wbs[kt * 4096 + t * 32 + ko]);
                s0 = fmaf(fmaxf(mv, 0.0f), w0, s0);
                ss = fmaf(mv, ws, ss);
            }
            rv0[b * 128 + t] = s0;
            rvS[b * 128 + t] = ss;
        }
        return;
    }
    const int l = t & 63, wv = t >> 6;
    const int g0 = blockIdx.x * 16 + wv * 4;   // wave's first cell (4 consecutive)
    const int pl = g0 >> 16;                   // uniform per block (NCELL % 16 == 0)
    const int* ordp = order + pl * BT;

    int n[4], st[4];
#pragma unroll
    for (int c = 0; c < 4; ++c) { n[c] = cnt[g0 + c]; st[c] = starts[g0 + c]; }

    uint v[4][4];
#pragma unroll
    for (int c = 0; c < 4; ++c) {
        if (n[c] > 0) {
            const int* op = ordp + st[c];
            int nm1 = n[c] - 1;
#pragma unroll
            for (int k = 0; k < 4; ++k) {
                int kk = k < nm1 ? k : nm1;
                v[c][k] = netu[(size_t)op[kk] * 64 + l];
            }
        }
    }
#pragma unroll
    for (int c = 0; c < 4; ++c) {
        if (n[c] > 0) {
            uint m = pk_max(pk_max(v[c][0], v[c][1]), pk_max(v[c][2], v[c][3]));
            const int* op = ordp + st[c];
            int nm1 = n[c] - 1;
            for (int k = 4; k < n[c]; k += 4) {  // rare tail (n > 4)
                int k1 = k + 1 < nm1 ? k + 1 : nm1;
                int k2 = k + 2 < nm1 ? k + 2 : nm1;
                int k3 = k + 3 < nm1 ? k + 3 : nm1;
                uint a = netu[(size_t)op[k] * 64 + l];
                uint b = netu[(size_t)op[k1] * 64 + l];
                uint cc = netu[(size_t)op[k2] * 64 + l];
                uint d = netu[(size_t)op[k3] * 64 + l];
                m = pk_max(m, pk_max(pk_max(a, b), pk_max(cc, d)));
            }
            segu[(size_t)(g0 + c) * 64 + l] = m;
        }
    }
}

// ---------- fused resblock (f16 MFMA, padded LDS, rank-1 mean, rank-3 p-fold) ----------
// LAST: fc_c fused — stage f16(out) in hT, run Wc pass, scatter c3 via rank maps.
template <int MODE, bool LAST>
__global__ __launch_bounds__(512, MODE == 0 ? 6 : 8) void k_resblock(
    const float* __restrict__ p, const uint* __restrict__ netu,
    const int4* __restrict__ idx4, const ushort* __restrict__ seg,
    const float* __restrict__ rv0, const float* __restrict__ rvS,
    const float* __restrict__ Wp, const float* __restrict__ bp,
    const float* __restrict__ M3, const float* __restrict__ bps,
    const ushort* __restrict__ wb0, const float* __restrict__ b0v,
    const ushort* __restrict__ wb1, const float* __restrict__ b1v,
    const ushort* __restrict__ wbs,
    ushort* __restrict__ out, float* __restrict__ meanW,
    const int* __restrict__ rank, const ushort* __restrict__ wbc,
    const float* __restrict__ bcv) {
    constexpr int LDA = (MODE == 0) ? 392 : 264;  // ushort stride; dwords ≡ 4 mod 32
    constexpr int NKT = (MODE == 0) ? 12 : 8;
    __shared__ __align__(16) ushort aT[64 * LDA];
    __shared__ float pS[MODE == 0 ? 192 : 1];  // MODE0: 64 rows x 3 f32
    __shared__ int rkS[LAST ? 192 : 1];
    ushort* hT = aT;  // alias: hidden tile after main loop; c-input staging for LAST
    const int t = threadIdx.x;  // 0..511
    const int rowBase = blockIdx.x * 64;
    const int bb = rowBase >> 13;

    if constexpr (LAST) {
        if (t < 192) rkS[t] = rank[(t >> 6) * BT + rowBase + (t & 63)];
    }

    if constexpr (MODE == 0) {
        if (t < 192) pS[t] = p[(size_t)rowBase * 3 + t];
        __syncthreads();
        for (int f = t; f < 3072; f += 512) {
            int row = f / 48, g = f - row * 48;
            float p0 = pS[row * 3 + 0], p1 = pS[row * 3 + 1], p2 = pS[row * 3 + 2];
            int k0 = g * 8;
            uint d[4];
#pragma unroll
            for (int w = 0; w < 4; ++w) {
                int k = k0 + 2 * w;
                float v0 = bp[k]     + p0 * Wp[k]     + p1 * Wp[384 + k]     + p2 * Wp[768 + k];
                float v1 = bp[k + 1] + p0 * Wp[k + 1] + p1 * Wp[384 + k + 1] + p2 * Wp[768 + k + 1];
                d[w] = f2h2(v0, v1);
            }
            *(uint4*)(aT + row * LDA + k0) = make_uint4(d[0], d[1], d[2], d[3]);
        }
    } else {
        const uint4* nsrc = (const uint4*)netu;
#pragma unroll
        for (int i = 0; i < 2; ++i) {  // net -> cols [0,128)
            int f = t + 512 * i;
            int row = f >> 4, cu = f & 15;
            *(uint4*)(aT + row * LDA + cu * 8) = nsrc[(size_t)(rowBase + row) * 16 + cu];
        }
#pragma unroll
        for (int i = 0; i < 2; ++i) {  // pooled (3-plane packed-f16 sum) -> cols [128,256)
            int f = t + 512 * i;
            int row = f >> 4, grp = f & 15;
            int4 cc = idx4[rowBase + row];
            uint4 A = *(const uint4*)(seg + ((size_t)cc.x) * 128 + grp * 8);
            uint4 B = *(const uint4*)(seg + ((size_t)NCELL + cc.y) * 128 + grp * 8);
            uint4 C = *(const uint4*)(seg + ((size_t)2 * NCELL + cc.z) * 128 + grp * 8);
            uint4 d;
            d.x = pk_add(pk_add(A.x, B.x), C.x);
            d.y = pk_add(pk_add(A.y, B.y), C.y);
            d.z = pk_add(pk_add(A.z, B.z), C.z);
            d.w = pk_add(pk_add(A.w, B.w), C.w);
            *(uint4*)(aT + row * LDA + 128 + grp * 8) = d;
        }
    }
    __syncthreads();

    const int l = t & 63, wid = t >> 6;  // wid 0..7
    const int n0 = wid * 16;
    const int lm = l & 15, lg = l >> 4;
    const ushort* w0 = wb0 + n0 * 32;
    const ushort* w1 = wb1 + n0 * 32;
    const ushort* ws = wbs + n0 * 32;

    f32x4 acc0[4], accS[4];
    {
        float bi;
        if constexpr (MODE == 0) bi = b0v[n0 + lm];
        else                     bi = rv0[bb * 128 + n0 + lm];
#pragma unroll
        for (int im = 0; im < 4; ++im) acc0[im] = bcast4(bi);
    }
    if constexpr (MODE == 1) {
        float si = rvS[bb * 128 + n0 + lm];
#pragma unroll
        for (int im = 0; im < 4; ++im) accS[im] = bcast4(si);
    }
#pragma unroll
    for (int kt = 0; kt < NKT; ++kt) {
        half8 b0 = *(const half8*)(w0 + kt * 4096 + lm * 32 + lg * 8);
        half8 bs;
        if constexpr (MODE == 1) bs = *(const half8*)(ws + kt * 4096 + lm * 32 + lg * 8);
#pragma unroll
        for (int im = 0; im < 4; ++im) {
            half8 a = *(const half8*)(aT + (im * 16 + lm) * LDA + kt * 32 + lg * 8);
            acc0[im] = mfma16(relu8(a), b0, acc0[im]);
            if constexpr (MODE == 1) accS[im] = mfma16(a, bs, accS[im]);
        }
    }
    if constexpr (MODE == 0) {
        int col = n0 + lm;
        float m0 = M3[col], m1 = M3[128 + col], m2 = M3[256 + col], bb2 = bps[col];
#pragma unroll
        for (int im = 0; im < 4; ++im)
#pragma unroll
            for (int j = 0; j < 4; ++j) {
                int row = im * 16 + lg * 4 + j;
                accS[im][j] = fmaf(pS[row * 3 + 0], m0,
                              fmaf(pS[row * 3 + 1], m1,
                              fmaf(pS[row * 3 + 2], m2, bb2)));
            }
    }
    __syncthreads();  // all waves done READING aT (and pS) before hT overwrites

    // h = relu(acc0) -> hT (aliases aT; stride 136, dwords 68 ≡ 4 mod 32)
#pragma unroll
    for (int im = 0; im < 4; ++im)
#pragma unroll
        for (int j = 0; j < 4; ++j) {
            int row = im * 16 + lg * 4 + j;
            hT[row * 136 + n0 + lm] = (ushort)f2h2(fmaxf(acc0[im][j], 0.0f), 0.0f);
        }
    __syncthreads();

    // accS += h @ W1
#pragma unroll
    for (int kt = 0; kt < 4; ++kt) {
        half8 b = *(const half8*)(w1 + kt * 4096 + lm * 32 + lg * 8);
#pragma unroll
        for (int im = 0; im < 4; ++im) {
            half8 a = *(const half8*)(hT + (im * 16 + lm) * 136 + kt * 32 + lg * 8);
            accS[im] = mfma16(a, b, accS[im]);
        }
    }

    if constexpr (!LAST) {
        // store out (f16) — direct scalar stores (L2 write-combines; r17 staging neutral)
#pragma unroll
        for (int im = 0; im < 4; ++im)
#pragma unroll
            for (int j = 0; j < 4; ++j) {
                int row = rowBase + im * 16 + lg * 4 + j;
                out[(size_t)row * 128 + n0 + lm] = (ushort)f2h2(accS[im][j], 0.0f);
            }
        // fused batch-mean (input to next block's meanvec); cols disjoint across waves
        if (meanW) {
            float s = 0.0f;
#pragma unroll
            for (int im = 0; im < 4; ++im)
#pragma unroll
                for (int j = 0; j < 4; ++j) s += accS[im][j];
            s += __shfl_xor(s, 16);
            s += __shfl_xor(s, 32);
            if (l < 16) atomicAdd(meanW + bb * 128 + n0 + l, s * (1.0f / 8192.0f));
        }
    } else {
        // fused fc_c: c_in = f16(accS) -> hT, then c = c_in @ Wc + bc -> c3 (3 copies)
        __syncthreads();  // all waves done READING hT (W1 pass)
#pragma unroll
        for (int im = 0; im < 4; ++im)
#pragma unroll
            for (int j = 0; j < 4; ++j) {
                int row = im * 16 + lg * 4 + j;
                hT[row * 136 + n0 + lm] = (ushort)f2h2(accS[im][j], 0.0f);
            }
        __syncthreads();
        f32x4 accC[4];
        {
            float ci = bcv[n0 + lm];
#pragma unroll
            for (int im = 0; im < 4; ++im) accC[im] = bcast4(ci);
        }
        const ushort* wc = wbc + n0 * 32;
#pragma unroll
        for (int kt = 0; kt < 4; ++kt) {
            half8 b = *(const half8*)(wc + kt * 4096 + lm * 32 + lg * 8);
#pragma unroll
            for (int im = 0; im < 4; ++im) {
                half8 a = *(const half8*)(hT + (im * 16 + lm) * 136 + kt * 32 + lg * 8);
                accC[im] = mfma16(a, b, accC[im]);
            }
        }
#pragma unroll
        for (int im = 0; im < 4; ++im)
#pragma unroll
            for (int j = 0; j < 4; ++j) {
                int row = im * 16 + lg * 4 + j;
                int col = n0 + lm;
                ushort v = (ushort)f2h2(accC[im][j], 0.0f);
                out[(size_t)rkS[row] * 128 + col] = v;
                out[((size_t)BT + rkS[64 + row]) * 128 + col] = v;
                out[((size_t)2 * BT + rkS[128 + row]) * 128 + col] = v;
            }
    }
}

// ---------- GEMM helper (k_fcc fallback only) ----------
__device__ __forceinline__ void mfma_gemm3(const ushort* __restrict__ aLDS, int lda, int nk,
                                           const ushort* __restrict__ wb, int lm, int lg,
                                           f32x4 acc[4][2]) {
    for (int kt = 0; kt < nk; ++kt) {
        half8 b0 = *(const half8*)(wb + kt * 4096 + lm * 32 + lg * 8);
        half8 b1 = *(const half8*)(wb + kt * 4096 + (16 + lm) * 32 + lg * 8);
#pragma unroll
        for (int im = 0; im < 4; ++im) {
            half8 a = *(const half8*)(aLDS + (im * 16 + lm) * lda + kt * 32 + lg * 8);
            acc[im][0] = mfma16(a, b0, acc[im][0]);
            acc[im][1] = mfma16(a, b1, acc[im][1]);
        }
    }
}

// ---------- fallback final projection (only when ws too small for fused path) ----------
__global__ __launch_bounds__(256, 2) void k_fcc(const uint* __restrict__ netu,
                                                const int* __restrict__ rank,
                                                const ushort* __restrict__ wbc,
                                                const float* __restrict__ bc,
                                                ushort* __restrict__ c3) {
    __shared__ __align__(16) ushort aT[64 * 136];
    __shared__ int rkS[3][64];
    const int t = threadIdx.x;
    const int rowBase = blockIdx.x * 64;
    if (t < 192) {
        int pl = t >> 6, rr = t & 63;
        rkS[pl][rr] = rank[pl * BT + rowBase + rr];
    }
    const uint4* nsrc = (const uint4*)netu;
#pragma unroll
    for (int i = 0; i < 4; ++i) {
        int u = t + 256 * i;
        int row = u >> 4, cu = u & 15;
        *(uint4*)(aT + row * 136 + cu * 8) = nsrc[(size_t)(rowBase + row) * 16 + cu];
    }
    __syncthreads();
    const int l = t & 63, wid = t >> 6;
    const int n0 = wid * 32;
    const int lm = l & 15, lg = l >> 4;
    f32x4 acc[4][2];
    {
        float ci0 = bc[n0 + lm], ci1 = bc[n0 + 16 + lm];
#pragma unroll
        for (int im = 0; im < 4; ++im) { acc[im][0] = bcast4(ci0); acc[im][1] = bcast4(ci1); }
    }
    mfma_gemm3(aT, 136, 4, wbc + n0 * 32, lm, lg, acc);
#pragma unroll
    for (int im = 0; im < 4; ++im)
#pragma unroll
        for (int ic = 0; ic < 2; ++ic)
#pragma unroll
            for (int j = 0; j < 4; ++j) {
                int row = im * 16 + lg * 4 + j;
                int col = n0 + ic * 16 + lm;
                ushort v = (ushort)f2h2(acc[im][ic][j], 0.0f);
                c3[(size_t)rkS[0][row] * 128 + col] = v;
                c3[((size_t)BT + rkS[1][row]) * 128 + col] = v;
                c3[((size_t)2 * BT + rkS[2][row]) * 128 + col] = v;
            }
}

// ---------- fused segmented-sum + transpose + divide over CONTIGUOUS runs ----------
// 32 cells/block (16.6 KB LDS -> 8 blocks/CU = 100% occupancy ceiling); 6144 blocks.
__global__ __launch_bounds__(256) void k_segfin(const uint* __restrict__ c3,
                                                const int* __restrict__ starts,
                                                const int* __restrict__ cnt,
                                                float* __restrict__ out) {
    __shared__ float tile[32 * 130];  // stride 130 dwords ≡ 2 mod 32 (2-way max)
    const int t = threadIdx.x;
    const int w = t >> 6, l = t & 63;
    const int bx = blockIdx.x;
    const int pl = bx >> 11;          // 2048 blocks per plane
    const int rem = bx & 2047;
    const int b = rem >> 7;
    const int cl0 = (rem & 127) << 5;  // 32 cells per block
    const int gbase = pl * NCELL + (b << 12) + cl0;

    for (int i = 0; i < 8; ++i) {
        int cellLocal = w * 8 + i;
        int g = gbase + cellLocal;
        int n = cnt[g];
        float s0 = 0.f, s1 = 0.f;
        if (n > 0) {
            size_t rowb = (size_t)pl * BT + starts[g];  // contiguous run
            int j = 0;
            for (; j + 4 <= n; j += 4) {
                uint a = c3[(rowb + j) * 64 + l];
                uint bq = c3[(rowb + j + 1) * 64 + l];
                uint c = c3[(rowb + j + 2) * 64 + l];
                uint d = c3[(rowb + j + 3) * 64 + l];
                s0 += (h2f_lo(a) + h2f_lo(bq)) + (h2f_lo(c) + h2f_lo(d));
                s1 += (h2f_hi(a) + h2f_hi(bq)) + (h2f_hi(c) + h2f_hi(d));
            }
            int rm = n - j;
            if (rm > 0) {
                uint a = c3[(rowb + j) * 64 + l];
                uint bq = (rm > 1) ? c3[(rowb + j + 1) * 64 + l] : 0u;
                uint c = (rm > 2) ? c3[(rowb + j + 2) * 64 + l] : 0u;
                s0 += h2f_lo(a) + (h2f_lo(bq) + h2f_lo(c));
                s1 += h2f_hi(a) + (h2f_hi(bq) + h2f_hi(c));
            }
        }
        *(float2*)(tile + cellLocal * 130 + 2 * l) = make_float2(s0, s1);
    }
    __syncthreads();

    // write: thread t -> cell (t & 31), channels [(t>>5)*16, +16)
    const int cell = t & 31;
    const int ch0 = (t >> 5) * 16;
    int cn = cnt[gbase + cell];
    float inv = cn > 0 ? 1.0f / (float)cn : 0.0f;
    size_t obase = (((size_t)((pl * 16 + b) * 128)) << 12) + cl0 + cell;
#pragma unroll
    for (int j = 0; j < 16; ++j) {
        int ch = ch0 + j;
        out[obase + ((size_t)ch << 12)] = tile[cell * 130 + ch] * inv;
    }
}

// ---------- launch ----------
extern "C" void kernel_launch(void* const* d_in, const int* in_sizes, int n_in,
                              void* d_out, int out_size, void* d_ws, size_t ws_size,
                              hipStream_t stream) {
    const float* p  = (const float*)d_in[0];
    const float* Wp = (const float*)d_in[1];
    const float* bp = (const float*)d_in[2];
    const float* W0 = (const float*)d_in[3];
    const float* b0 = (const float*)d_in[4];
    const float* W1 = (const float*)d_in[5];
    const float* b1 = (const float*)d_in[6];
    const float* Ws = (const float*)d_in[7];
    const float* Wc = (const float*)d_in[8];
    const float* bc = (const float*)d_in[9];
    float* out = (float*)d_out;

    // Fused path needs seg separate from c3 (LAST resblock reads seg + writes c3).
    // Layout (ushorts from base): c3 | seg(?) | net | wb | ints | idx4 | floats.
    const size_t NEED_FUSED = 196u * 1024 * 1024;  // ~196 MB with margin
    const bool fused = ws_size >= NEED_FUSED;

    ushort* c3  = (ushort*)d_ws;                          // 96 MB
    ushort* seg = fused ? (c3 + 50331648) : c3;           // separate 48 MB or alias
    ushort* net = seg + 25165824;                         // 32 MB
    ushort* wb  = net + 16777216;
    int*    idx    = (int*)(wb + 589824);
    int*    order  = idx + 393216;
    int*    rank   = order + 393216;
    int*    cnt    = rank + 393216;
    int*    starts = cnt + 196608;
    int*    cursor = starts + 196608;
    int4*   idx4   = (int4*)(cursor + 196608);
    float*  meanB  = (float*)(idx4 + 131072);
    float*  rv0    = meanB + 4 * 2048;
    float*  rvS    = rv0 + 2048;
    float*  M3     = rvS + 2048;
    float*  bps    = M3 + 384;

    // --- sort points by cell (loop-invariant) + weight convert + p-fold ---
    k_idx<<<512, 256, 0, stream>>>(p, idx, idx4);
    (void)hipMemsetAsync(cnt, 0, 3 * NCELL * 4, stream);
    k_hist<<<512, 256, 0, stream>>>(idx, cnt);
    k_scan<<<3, 1024, 0, stream>>>(cnt, starts, cursor);
    k_scatter_order<<<512, 256, 0, stream>>>(idx, cursor, order, rank);
    k_wconv<<<dim3(192, 16), 256, 0, stream>>>(W0, W1, Ws, Wc, wb);
    k_pfold<<<1, 128, 0, stream>>>(Wp, bp, Ws, b1, M3, bps);
    (void)hipMemsetAsync(meanB, 0, 4 * 2048 * 4, stream);

    // --- block 0 (fc_pos fused, shortcut folded), writes mean slot 0 ---
    k_resblock<0, false><<<2048, 512, 0, stream>>>(
        p, nullptr, nullptr, nullptr, nullptr, nullptr, Wp, bp, M3, bps,
        wb, b0, wb + 245760, b1, wb + 327680, net, meanB,
        nullptr, nullptr, nullptr);

    for (int i = 1; i < NB; ++i) {
        const ushort* wb0i = wb + (size_t)i * 49152;
        const ushort* wb1i = wb + 245760 + (size_t)i * 16384;
        const ushort* wbsi = wb + 327680 + (size_t)i * 49152;
        k_segmax<<<12304, 256, 0, stream>>>((const uint*)net, starts, cnt, order, (uint*)seg,
                                            meanB + (i - 1) * 2048, wb0i, b0 + i * 128,
                                            wbsi, b1 + i * 128, rv0, rvS);
        const bool isLast = (i == NB - 1);
        float* mw = isLast ? nullptr : meanB + i * 2048;
        if (isLast && fused) {
            // fc_c fused: writes c3 directly (seg is a separate buffer — no alias race)
            k_resblock<1, true><<<2048, 512, 0, stream>>>(
                nullptr, (const uint*)net, idx4, seg, rv0, rvS, nullptr, nullptr,
                nullptr, nullptr, wb0i, nullptr, wb1i, nullptr, wbsi, c3, nullptr,
                rank, wb + 573440, bc);
        } else {
            k_resblock<1, false><<<2048, 512, 0, stream>>>(
                nullptr, (const uint*)net, idx4, seg, rv0, rvS, nullptr, nullptr,
                nullptr, nullptr, wb0i, nullptr, wb1i, nullptr, wbsi, net, mw,
                nullptr, nullptr, nullptr);
        }
    }

    if (!fused) {
        // fallback: separate projection (seg aliases c3; safe — different kernels)
        k_fcc<<<2048, 256, 0, stream>>>((const uint*)net, rank, wb + 573440, bc, c3);
    }

    // --- fused segmented sum + transpose + divide, contiguous runs (32-cell tiles) ---
    k_segfin<<<6144, 256, 0, stream>>>((const uint*)c3, starts, cnt, out);
}

// Round 19
// 635.538 us; speedup vs baseline: 1.0198x; 1.0007x over previous
//
#include <hip/hip_runtime.h>

#define BT (16 * 8192)
#define NB 5
#define NCELL 65536  // B * RESO^2
typedef unsigned int uint;
typedef unsigned short ushort;
typedef __attribute__((ext_vector_type(8))) _Float16 half8;
typedef __attribute__((ext_vector_type(2))) __fp16 fp16x2;
typedef __attribute__((ext_vector_type(2))) _Float16 half2v;
typedef __attribute__((ext_vector_type(4))) float f32x4;

// NOTE (r5): aT lda dwords ≡ 4 mod 32 -> natural bank stagger; NO XOR swizzle.
// NOTE (r7/r9): resblock neither MFMA- nor VALU-bound. NOTE (r11): never alias a
// buffer read and written by the SAME kernel. NOTE (r17): scalar stores to CONTIGUOUS
// dest don't amplify (L2 combines). NOTE (r18): scalar stores to SCATTERED rows DO
// amplify (127MB vs 96MB) — 8 waves partial-write each 256B sector at different times.
// This round: LAST kernel stages c3 rows in LDS and writes full 256B rows as uint4
// (one wave-instruction per row); fold k_hist into k_idx, k_pfold into k_wconv.

// ---------- fp16 helpers ----------
__device__ __forceinline__ uint f2h2(float a, float b) {
    fp16x2 h = __builtin_amdgcn_cvt_pkrtz(a, b);
    return *(uint*)&h;
}
__device__ __forceinline__ float h2f_lo(uint u) { half2v h = *(half2v*)&u; return (float)h[0]; }
__device__ __forceinline__ float h2f_hi(uint u) { half2v h = *(half2v*)&u; return (float)h[1]; }
__device__ __forceinline__ uint pk_add(uint a, uint b) {
    uint d; asm("v_pk_add_f16 %0, %1, %2" : "=v"(d) : "v"(a), "v"(b)); return d;
}
__device__ __forceinline__ uint pk_max(uint a, uint b) {
    uint d; asm("v_pk_max_f16 %0, %1, %2" : "=v"(d) : "v"(a), "v"(b)); return d;
}

// relu on packed f16: single v_pk_max_f16 with +0 per dword
__device__ __forceinline__ half8 relu8(half8 a) {
    uint4 u = *(uint4*)&a;
    u.x = pk_max(u.x, 0u); u.y = pk_max(u.y, 0u);
    u.z = pk_max(u.z, 0u); u.w = pk_max(u.w, 0u);
    return *(half8*)&u;
}
__device__ __forceinline__ f32x4 bcast4(float x) { return (f32x4){x, x, x, x}; }
__device__ __forceinline__ f32x4 mfma16(half8 a, half8 b, f32x4 c) {
    return __builtin_amdgcn_mfma_f32_16x16x32_f16(a, b, c, 0, 0, 0);
}

// ---------- plane indices + histogram (fused; bitwise-identical idx math) ----------
__global__ void k_idx(const float* __restrict__ p, int* __restrict__ idx,
                      int4* __restrict__ idx4, int* __restrict__ cnt) {
    int r = blockIdx.x * 256 + threadIdx.x;
    if (r >= BT) return;
    float p0 = p[3 * r + 0], p1 = p[3 * r + 1], p2 = p[3 * r + 2];
    const float DEN = (float)(1.0 + 0.1 + 1e-3);
    const float HI  = (float)(1.0 - 1e-5);
    int b = r >> 13;  // T = 8192
    float x0 = fminf(fmaxf((p0 / 8.0f) / DEN + 0.5f, 0.0f), HI);
    float x1 = fminf(fmaxf((p1 / 8.0f) / DEN + 0.5f, 0.0f), HI);
    float x2 = fminf(fmaxf((p2 / 8.0f) / DEN + 0.5f, 0.0f), HI);
    int i0 = (int)(x0 * 64.0f);
    int i1 = (int)(x1 * 64.0f);
    int i2 = (int)(x2 * 64.0f);
    int base = b << 12;
    int exz = base + i0 + (i2 << 6);
    int exy = base + i0 + (i1 << 6);
    int eyz = base + i1 + (i2 << 6);
    idx[r] = exz; idx[BT + r] = exy; idx[2 * BT + r] = eyz;
    idx4[r] = make_int4(exz, exy, eyz, 0);
    atomicAdd(cnt + exz, 1);
    atomicAdd(cnt + NCELL + exy, 1);
    atomicAdd(cnt + 2 * NCELL + eyz, 1);
}

__global__ __launch_bounds__(1024) void k_scan(const int* __restrict__ cnt,
                                               int* __restrict__ starts,
                                               int* __restrict__ cursor) {
    __shared__ int sc[1024];
    int pl = blockIdx.x, t = threadIdx.x;
    const int* c = cnt + pl * NCELL;
    int base = t * 64;
    int s = 0;
    for (int i = 0; i < 64; ++i) s += c[base + i];
    sc[t] = s;
    __syncthreads();
    for (int off = 1; off < 1024; off <<= 1) {
        int v = (t >= off) ? sc[t - off] : 0;
        __syncthreads();
        sc[t] += v;
        __syncthreads();
    }
    int run = sc[t] - s;
    for (int i = 0; i < 64; ++i) {
        int cell = base + i;
        starts[pl * NCELL + cell] = run;
        cursor[pl * NCELL + cell] = run;
        run += c[cell];
    }
}

// order[pl][pos] = point id; rank[pl][r] = pos (inverse permutation)
__global__ void k_scatter_order(const int* __restrict__ idx, int* __restrict__ cursor,
                                int* __restrict__ order, int* __restrict__ rank) {
    int r = blockIdx.x * 256 + threadIdx.x;
    if (r >= BT) return;
    for (int pl = 0; pl < 3; ++pl) {
        int cell = idx[pl * BT + r];
        int pos = atomicAdd(cursor + pl * NCELL + cell, 1);
        order[pl * BT + pos] = r;
        rank[pl * BT + r] = pos;
    }
}

// ---------- weight convert + p-fold (fused; pfold = grid row y==16, block x==0) ----------
__global__ void k_wconv(const float* __restrict__ W0, const float* __restrict__ W1,
                        const float* __restrict__ Ws, const float* __restrict__ Wc,
                        ushort* __restrict__ wb, const float* __restrict__ Wp,
                        const float* __restrict__ bp, const float* __restrict__ b1v,
                        float* __restrict__ M3, float* __restrict__ bps) {
    int mat = blockIdx.y;
    if (mat == 16) {  // p-fold: M3 = Wp @ Ws0 (3x128), bps = bp @ Ws0 + b1
        if (blockIdx.x != 0) return;
        int n = threadIdx.x;
        if (n >= 128) return;
        float s0 = 0.f, s1 = 0.f, s2 = 0.f, sb = b1v[n];
        for (int k = 0; k < 384; ++k) {
            float w = Ws[(size_t)k * 128 + n];
            s0 = fmaf(Wp[k], w, s0);
            s1 = fmaf(Wp[384 + k], w, s1);
            s2 = fmaf(Wp[768 + k], w, s2);
            sb = fmaf(bp[k], w, sb);
        }
        M3[n] = s0; M3[128 + n] = s1; M3[256 + n] = s2;
        bps[n] = sb;
        return;
    }
    int K = (mat < 5 || (mat >= 10 && mat < 15)) ? 384 : 128;
    int e = blockIdx.x * 256 + threadIdx.x;
    if (e >= K * 128) return;
    const float* src;
    size_t doff;
    if (mat < 5)       { src = W0 + (size_t)mat * 49152;        doff = (size_t)mat * 49152; }
    else if (mat < 10) { src = W1 + (size_t)(mat - 5) * 16384;  doff = 245760 + (size_t)(mat - 5) * 16384; }
    else if (mat < 15) { src = Ws + (size_t)(mat - 10) * 49152; doff = 327680 + (size_t)(mat - 10) * 49152; }
    else               { src = Wc;                              doff = 573440; }
    int ko = e & 31, n = (e >> 5) & 127, kt = e >> 12;
    wb[doff + e] = (ushort)f2h2(src[(size_t)(kt * 32 + ko) * 128 + n], 0.0f);
}

// ---------- segmented max: 4 cells per wave, batched gathers + meanvec tail ----------
__global__ __launch_bounds__(256) void k_segmax(const uint* __restrict__ netu,
                                                const int* __restrict__ starts,
                                                const int* __restrict__ cnt,
                                                const int* __restrict__ order,
                                                uint* __restrict__ segu,
                                                const float* __restrict__ meanPrev,
                                                const ushort* __restrict__ wb0,
                                                const float* __restrict__ b0v,
                                                const ushort* __restrict__ wbs,
                                                const float* __restrict__ b1v,
                                                float* __restrict__ rv0,
                                                float* __restrict__ rvS) {
    int t = threadIdx.x;
    if (blockIdx.x >= 12288) {
        __shared__ float ms[128];
        int b = blockIdx.x - 12288;
        if (t < 128) ms[t] = meanPrev[b * 128 + t];
        __syncthreads();
        if (t < 128) {
            float s0 = b0v[t], ss = b1v[t];
#pragma unroll 4
            for (int k = 0; k < 128; ++k) {
                float mv = ms[k];
                int kt = 8 + (k >> 5), ko = k & 31;
                float w0 = h2f_lo((uint)wb0[kt * 4096 + t * 32 + ko]);
                float ws = h2f_lo((uint)wbs[kt * 4096 + t * 32 + ko]);
                s0 = fmaf(fmaxf(mv, 0.0f), w0, s0);
                ss = fmaf(mv, ws, ss);
            }
            rv0[b * 128 + t] = s0;
            rvS[b * 128 + t] = ss;
        }
        return;
    }
    const int l = t & 63, wv = t >> 6;
    const int g0 = blockIdx.x * 16 + wv * 4;   // wave's first cell (4 consecutive)
    const int pl = g0 >> 16;                   // uniform per block (NCELL % 16 == 0)
    const int* ordp = order + pl * BT;

    int n[4], st[4];
#pragma unroll
    for (int c = 0; c < 4; ++c) { n[c] = cnt[g0 + c]; st[c] = starts[g0 + c]; }

    uint v[4][4];
#pragma unroll
    for (int c = 0; c < 4; ++c) {
        if (n[c] > 0) {
            const int* op = ordp + st[c];
            int nm1 = n[c] - 1;
#pragma unroll
            for (int k = 0; k < 4; ++k) {
                int kk = k < nm1 ? k : nm1;
                v[c][k] = netu[(size_t)op[kk] * 64 + l];
            }
        }
    }
#pragma unroll
    for (int c = 0; c < 4; ++c) {
        if (n[c] > 0) {
            uint m = pk_max(pk_max(v[c][0], v[c][1]), pk_max(v[c][2], v[c][3]));
            const int* op = ordp + st[c];
            int nm1 = n[c] - 1;
            for (int k = 4; k < n[c]; k += 4) {  // rare tail (n > 4)
                int k1 = k + 1 < nm1 ? k + 1 : nm1;
                int k2 = k + 2 < nm1 ? k + 2 : nm1;
                int k3 = k + 3 < nm1 ? k + 3 : nm1;
                uint a = netu[(size_t)op[k] * 64 + l];
                uint b = netu[(size_t)op[k1] * 64 + l];
                uint cc = netu[(size_t)op[k2] * 64 + l];
                uint d = netu[(size_t)op[k3] * 64 + l];
                m = pk_max(m, pk_max(pk_max(a, b), pk_max(cc, d)));
            }
            segu[(size_t)(g0 + c) * 64 + l] = m;
        }
    }
}

// ---------- fused resblock (f16 MFMA, padded LDS, rank-1 mean, rank-3 p-fold) ----------
// LAST: fc_c fused — Wc pass over hT, then ROW-STAGED c3 writes (full 256B rows).
template <int MODE, bool LAST>
__global__ __launch_bounds__(512, MODE == 0 ? 6 : 8) void k_resblock(
    const float* __restrict__ p, const uint* __restrict__ netu,
    const int4* __restrict__ idx4, const ushort* __restrict__ seg,
    const float* __restrict__ rv0, const float* __restrict__ rvS,
    const float* __restrict__ Wp, const float* __restrict__ bp,
    const float* __restrict__ M3, const float* __restrict__ bps,
    const ushort* __restrict__ wb0, const float* __restrict__ b0v,
    const ushort* __restrict__ wb1, const float* __restrict__ b1v,
    const ushort* __restrict__ wbs,
    ushort* __restrict__ out, float* __restrict__ meanW,
    const int* __restrict__ rank, const ushort* __restrict__ wbc,
    const float* __restrict__ bcv) {
    constexpr int LDA = (MODE == 0) ? 392 : 264;  // ushort stride; dwords ≡ 4 mod 32
    constexpr int NKT = (MODE == 0) ? 12 : 8;
    __shared__ __align__(16) ushort aT[64 * LDA];
    __shared__ float pS[MODE == 0 ? 192 : 1];  // MODE0: 64 rows x 3 f32
    __shared__ int rkS[LAST ? 192 : 1];
    ushort* hT = aT;  // alias: hidden tile; c-input staging; c-output staging (LAST)
    const int t = threadIdx.x;  // 0..511
    const int rowBase = blockIdx.x * 64;
    const int bb = rowBase >> 13;

    if constexpr (LAST) {
        if (t < 192) rkS[t] = rank[(t >> 6) * BT + rowBase + (t & 63)];
    }

    if constexpr (MODE == 0) {
        if (t < 192) pS[t] = p[(size_t)rowBase * 3 + t];
        __syncthreads();
        for (int f = t; f < 3072; f += 512) {
            int row = f / 48, g = f - row * 48;
            float p0 = pS[row * 3 + 0], p1 = pS[row * 3 + 1], p2 = pS[row * 3 + 2];
            int k0 = g * 8;
            uint d[4];
#pragma unroll
            for (int w = 0; w < 4; ++w) {
                int k = k0 + 2 * w;
                float v0 = bp[k]     + p0 * Wp[k]     + p1 * Wp[384 + k]     + p2 * Wp[768 + k];
                float v1 = bp[k + 1] + p0 * Wp[k + 1] + p1 * Wp[384 + k + 1] + p2 * Wp[768 + k + 1];
                d[w] = f2h2(v0, v1);
            }
            *(uint4*)(aT + row * LDA + k0) = make_uint4(d[0], d[1], d[2], d[3]);
        }
    } else {
        const uint4* nsrc = (const uint4*)netu;
#pragma unroll
        for (int i = 0; i < 2; ++i) {  // net -> cols [0,128)
            int f = t + 512 * i;
            int row = f >> 4, cu = f & 15;
            *(uint4*)(aT + row * LDA + cu * 8) = nsrc[(size_t)(rowBase + row) * 16 + cu];
        }
#pragma unroll
        for (int i = 0; i < 2; ++i) {  // pooled (3-plane packed-f16 sum) -> cols [128,256)
            int f = t + 512 * i;
            int row = f >> 4, grp = f & 15;
            int4 cc = idx4[rowBase + row];
            uint4 A = *(const uint4*)(seg + ((size_t)cc.x) * 128 + grp * 8);
            uint4 B = *(const uint4*)(seg + ((size_t)NCELL + cc.y) * 128 + grp * 8);
            uint4 C = *(const uint4*)(seg + ((size_t)2 * NCELL + cc.z) * 128 + grp * 8);
            uint4 d;
            d.x = pk_add(pk_add(A.x, B.x), C.x);
            d.y = pk_add(pk_add(A.y, B.y), C.y);
            d.z = pk_add(pk_add(A.z, B.z), C.z);
            d.w = pk_add(pk_add(A.w, B.w), C.w);
            *(uint4*)(aT + row * LDA + 128 + grp * 8) = d;
        }
    }
    __syncthreads();

    const int l = t & 63, wid = t >> 6;  // wid 0..7
    const int n0 = wid * 16;
    const int lm = l & 15, lg = l >> 4;
    const ushort* w0 = wb0 + n0 * 32;
    const ushort* w1 = wb1 + n0 * 32;
    const ushort* ws = wbs + n0 * 32;

    f32x4 acc0[4], accS[4];
    {
        float bi;
        if constexpr (MODE == 0) bi = b0v[n0 + lm];
        else                     bi = rv0[bb * 128 + n0 + lm];
#pragma unroll
        for (int im = 0; im < 4; ++im) acc0[im] = bcast4(bi);
    }
    if constexpr (MODE == 1) {
        float si = rvS[bb * 128 + n0 + lm];
#pragma unroll
        for (int im = 0; im < 4; ++im) accS[im] = bcast4(si);
    }
#pragma unroll
    for (int kt = 0; kt < NKT; ++kt) {
        half8 b0 = *(const half8*)(w0 + kt * 4096 + lm * 32 + lg * 8);
        half8 bs;
        if constexpr (MODE == 1) bs = *(const half8*)(ws + kt * 4096 + lm * 32 + lg * 8);
#pragma unroll
        for (int im = 0; im < 4; ++im) {
            half8 a = *(const half8*)(aT + (im * 16 + lm) * LDA + kt * 32 + lg * 8);
            acc0[im] = mfma16(relu8(a), b0, acc0[im]);
            if constexpr (MODE == 1) accS[im] = mfma16(a, bs, accS[im]);
        }
    }
    if constexpr (MODE == 0) {
        int col = n0 + lm;
        float m0 = M3[col], m1 = M3[128 + col], m2 = M3[256 + col], bb2 = bps[col];
#pragma unroll
        for (int im = 0; im < 4; ++im)
#pragma unroll
            for (int j = 0; j < 4; ++j) {
                int row = im * 16 + lg * 4 + j;
                accS[im][j] = fmaf(pS[row * 3 + 0], m0,
                              fmaf(pS[row * 3 + 1], m1,
                              fmaf(pS[row * 3 + 2], m2, bb2)));
            }
    }
    __syncthreads();  // all waves done READING aT (and pS) before hT overwrites

    // h = relu(acc0) -> hT (aliases aT; stride 136, dwords 68 ≡ 4 mod 32)
#pragma unroll
    for (int im = 0; im < 4; ++im)
#pragma unroll
        for (int j = 0; j < 4; ++j) {
            int row = im * 16 + lg * 4 + j;
            hT[row * 136 + n0 + lm] = (ushort)f2h2(fmaxf(acc0[im][j], 0.0f), 0.0f);
        }
    __syncthreads();

    // accS += h @ W1
#pragma unroll
    for (int kt = 0; kt < 4; ++kt) {
        half8 b = *(const half8*)(w1 + kt * 4096 + lm * 32 + lg * 8);
#pragma unroll
        for (int im = 0; im < 4; ++im) {
            half8 a = *(const half8*)(hT + (im * 16 + lm) * 136 + kt * 32 + lg * 8);
            accS[im] = mfma16(a, b, accS[im]);
        }
    }

    if constexpr (!LAST) {
        // store out (f16) — contiguous dest: scalar stores combine fine in L2 (r17)
#pragma unroll
        for (int im = 0; im < 4; ++im)
#pragma unroll
            for (int j = 0; j < 4; ++j) {
                int row = rowBase + im * 16 + lg * 4 + j;
                out[(size_t)row * 128 + n0 + lm] = (ushort)f2h2(accS[im][j], 0.0f);
            }
        // fused batch-mean (input to next block's meanvec); cols disjoint across waves
        if (meanW) {
            float s = 0.0f;
#pragma unroll
            for (int im = 0; im < 4; ++im)
#pragma unroll
                for (int j = 0; j < 4; ++j) s += accS[im][j];
            s += __shfl_xor(s, 16);
            s += __shfl_xor(s, 32);
            if (l < 16) atomicAdd(meanW + bb * 128 + n0 + l, s * (1.0f / 8192.0f));
        }
    } else {
        // fused fc_c: c_in = f16(accS) -> hT, c = c_in @ Wc + bc, then ROW-STAGED writes
        __syncthreads();  // all waves done READING hT (W1 pass)
#pragma unroll
        for (int im = 0; im < 4; ++im)
#pragma unroll
            for (int j = 0; j < 4; ++j) {
                int row = im * 16 + lg * 4 + j;
                hT[row * 136 + n0 + lm] = (ushort)f2h2(accS[im][j], 0.0f);
            }
        __syncthreads();
        f32x4 accC[4];
        {
            float ci = bcv[n0 + lm];
#pragma unroll
            for (int im = 0; im < 4; ++im) accC[im] = bcast4(ci);
        }
        const ushort* wc = wbc + n0 * 32;
#pragma unroll
        for (int kt = 0; kt < 4; ++kt) {
            half8 b = *(const half8*)(wc + kt * 4096 + lm * 32 + lg * 8);
#pragma unroll
            for (int im = 0; im < 4; ++im) {
                half8 a = *(const half8*)(hT + (im * 16 + lm) * 136 + kt * 32 + lg * 8);
                accC[im] = mfma16(a, b, accC[im]);
            }
        }
        __syncthreads();  // all waves done READING hT (Wc pass)
        // stage c-output into hT
#pragma unroll
        for (int im = 0; im < 4; ++im)
#pragma unroll
            for (int j = 0; j < 4; ++j) {
                int row = im * 16 + lg * 4 + j;
                hT[row * 136 + n0 + lm] = (ushort)f2h2(accC[im][j], 0.0f);
            }
        __syncthreads();
        // write 3 copies: 16 consecutive lanes emit one full 256B row per copy
#pragma unroll
        for (int i = 0; i < 2; ++i) {
            int f = t + 512 * i;
            int row = f >> 4, cu = f & 15;
            uint4 v = *(const uint4*)(hT + row * 136 + cu * 8);
            *(uint4*)(out + (size_t)rkS[row] * 128 + cu * 8) = v;
            *(uint4*)(out + ((size_t)BT + rkS[64 + row]) * 128 + cu * 8) = v;
            *(uint4*)(out + ((size_t)2 * BT + rkS[128 + row]) * 128 + cu * 8) = v;
        }
    }
}

// ---------- GEMM helper (k_fcc fallback only) ----------
__device__ __forceinline__ void mfma_gemm3(const ushort* __restrict__ aLDS, int lda, int nk,
                                           const ushort* __restrict__ wb, int lm, int lg,
                                           f32x4 acc[4][2]) {
    for (int kt = 0; kt < nk; ++kt) {
        half8 b0 = *(const half8*)(wb + kt * 4096 + lm * 32 + lg * 8);
        half8 b1 = *(const half8*)(wb + kt * 4096 + (16 + lm) * 32 + lg * 8);
#pragma unroll
        for (int im = 0; im < 4; ++im) {
            half8 a = *(const half8*)(aLDS + (im * 16 + lm) * lda + kt * 32 + lg * 8);
            acc[im][0] = mfma16(a, b0, acc[im][0]);
            acc[im][1] = mfma16(a, b1, acc[im][1]);
        }
    }
}

// ---------- fallback final projection (only when ws too small for fused path) ----------
__global__ __launch_bounds__(256, 2) void k_fcc(const uint* __restrict__ netu,
                                                const int* __restrict__ rank,
                                                const ushort* __restrict__ wbc,
                                                const float* __restrict__ bc,
                                                ushort* __restrict__ c3) {
    __shared__ __align__(16) ushort aT[64 * 136];
    __shared__ int rkS[3][64];
    const int t = threadIdx.x;
    const int rowBase = blockIdx.x * 64;
    if (t < 192) {
        int pl = t >> 6, rr = t & 63;
        rkS[pl][rr] = rank[pl * BT + rowBase + rr];
    }
    const uint4* nsrc = (const uint4*)netu;
#pragma unroll
    for (int i = 0; i < 4; ++i) {
        int u = t + 256 * i;
        int row = u >> 4, cu = u & 15;
        *(uint4*)(aT + row * 136 + cu * 8) = nsrc[(size_t)(rowBase + row) * 16 + cu];
    }
    __syncthreads();
    const int l = t & 63, wid = t >> 6;
    const int n0 = wid * 32;
    const int lm = l & 15, lg = l >> 4;
    f32x4 acc[4][2];
    {
        float ci0 = bc[n0 + lm], ci1 = bc[n0 + 16 + lm];
#pragma unroll
        for (int im = 0; im < 4; ++im) { acc[im][0] = bcast4(ci0); acc[im][1] = bcast4(ci1); }
    }
    mfma_gemm3(aT, 136, 4, wbc + n0 * 32, lm, lg, acc);
#pragma unroll
    for (int im = 0; im < 4; ++im)
#pragma unroll
        for (int ic = 0; ic < 2; ++ic)
#pragma unroll
            for (int j = 0; j < 4; ++j) {
                int row = im * 16 + lg * 4 + j;
                int col = n0 + ic * 16 + lm;
                ushort v = (ushort)f2h2(acc[im][ic][j], 0.0f);
                c3[(size_t)rkS[0][row] * 128 + col] = v;
                c3[((size_t)BT + rkS[1][row]) * 128 + col] = v;
                c3[((size_t)2 * BT + rkS[2][row]) * 128 + col] = v;
            }
}

// ---------- fused segmented-sum + transpose + divide over CONTIGUOUS runs ----------
// 32 cells/block (16.6 KB LDS -> 8 blocks/CU = 100% occupancy ceiling); 6144 blocks.
__global__ __launch_bounds__(256) void k_segfin(const uint* __restrict__ c3,
                                                const int* __restrict__ starts,
                                                const int* __restrict__ cnt,
                                                float* __restrict__ out) {
    __shared__ float tile[32 * 130];  // stride 130 dwords ≡ 2 mod 32 (2-way max)
    const int t = threadIdx.x;
    const int w = t >> 6, l = t & 63;
    const int bx = blockIdx.x;
    const int pl = bx >> 11;          // 2048 blocks per plane
    const int rem = bx & 2047;
    const int b = rem >> 7;
    const int cl0 = (rem & 127) << 5;  // 32 cells per block
    const int gbase = pl * NCELL + (b << 12) + cl0;

    for (int i = 0; i < 8; ++i) {
        int cellLocal = w * 8 + i;
        int g = gbase + cellLocal;
        int n = cnt[g];
        float s0 = 0.f, s1 = 0.f;
        if (n > 0) {
            size_t rowb = (size_t)pl * BT + starts[g];  // contiguous run
            int j = 0;
            for (; j + 4 <= n; j += 4) {
                uint a = c3[(rowb + j) * 64 + l];
                uint bq = c3[(rowb + j + 1) * 64 + l];
                uint c = c3[(rowb + j + 2) * 64 + l];
                uint d = c3[(rowb + j + 3) * 64 + l];
                s0 += (h2f_lo(a) + h2f_lo(bq)) + (h2f_lo(c) + h2f_lo(d));
                s1 += (h2f_hi(a) + h2f_hi(bq)) + (h2f_hi(c) + h2f_hi(d));
            }
            int rm = n - j;
            if (rm > 0) {
                uint a = c3[(rowb + j) * 64 + l];
                uint bq = (rm > 1) ? c3[(rowb + j + 1) * 64 + l] : 0u;
                uint c = (rm > 2) ? c3[(rowb + j + 2) * 64 + l] : 0u;
                s0 += h2f_lo(a) + (h2f_lo(bq) + h2f_lo(c));
                s1 += h2f_hi(a) + (h2f_hi(bq) + h2f_hi(c));
            }
        }
        *(float2*)(tile + cellLocal * 130 + 2 * l) = make_float2(s0, s1);
    }
    __syncthreads();

    // write: thread t -> cell (t & 31), channels [(t>>5)*16, +16)
    const int cell = t & 31;
    const int ch0 = (t >> 5) * 16;
    int cn = cnt[gbase + cell];
    float inv = cn > 0 ? 1.0f / (float)cn : 0.0f;
    size_t obase = (((size_t)((pl * 16 + b) * 128)) << 12) + cl0 + cell;
#pragma unroll
    for (int j = 0; j < 16; ++j) {
        int ch = ch0 + j;
        out[obase + ((size_t)ch << 12)] = tile[cell * 130 + ch] * inv;
    }
}

// ---------- launch ----------
extern "C" void kernel_launch(void* const* d_in, const int* in_sizes, int n_in,
                              void* d_out, int out_size, void* d_ws, size_t ws_size,
                              hipStream_t stream) {
    const float* p  = (const float*)d_in[0];
    const float* Wp = (const float*)d_in[1];
    const float* bp = (const float*)d_in[2];
    const float* W0 = (const float*)d_in[3];
    const float* b0 = (const float*)d_in[4];
    const float* W1 = (const float*)d_in[5];
    const float* b1 = (const float*)d_in[6];
    const float* Ws = (const float*)d_in[7];
    const float* Wc = (const float*)d_in[8];
    const float* bc = (const float*)d_in[9];
    float* out = (float*)d_out;

    // Fused path needs seg separate from c3 (LAST resblock reads seg + writes c3).
    const size_t NEED_FUSED = 196u * 1024 * 1024;  // ~196 MB with margin
    const bool fused = ws_size >= NEED_FUSED;

    ushort* c3  = (ushort*)d_ws;                          // 96 MB
    ushort* seg = fused ? (c3 + 50331648) : c3;           // separate 48 MB or alias
    ushort* net = seg + 25165824;                         // 32 MB
    ushort* wb  = net + 16777216;
    int*    idx    = (int*)(wb + 589824);
    int*    order  = idx + 393216;
    int*    rank   = order + 393216;
    int*    cnt    = rank + 393216;
    int*    starts = cnt + 196608;
    int*    cursor = starts + 196608;
    int4*   idx4   = (int4*)(cursor + 196608);
    float*  meanB  = (float*)(idx4 + 131072);
    float*  rv0    = meanB + 4 * 2048;
    float*  rvS    = rv0 + 2048;
    float*  M3     = rvS + 2048;
    float*  bps    = M3 + 384;

    // --- sort points by cell (loop-invariant) + weight convert + p-fold ---
    (void)hipMemsetAsync(cnt, 0, 3 * NCELL * 4, stream);
    k_idx<<<512, 256, 0, stream>>>(p, idx, idx4, cnt);           // idx + histogram fused
    k_scan<<<3, 1024, 0, stream>>>(cnt, starts, cursor);
    k_scatter_order<<<512, 256, 0, stream>>>(idx, cursor, order, rank);
    k_wconv<<<dim3(192, 17), 256, 0, stream>>>(W0, W1, Ws, Wc, wb, Wp, bp, b1, M3, bps);
    (void)hipMemsetAsync(meanB, 0, 4 * 2048 * 4, stream);

    // --- block 0 (fc_pos fused, shortcut folded), writes mean slot 0 ---
    k_resblock<0, false><<<2048, 512, 0, stream>>>(
        p, nullptr, nullptr, nullptr, nullptr, nullptr, Wp, bp, M3, bps,
        wb, b0, wb + 245760, b1, wb + 327680, net, meanB,
        nullptr, nullptr, nullptr);

    for (int i = 1; i < NB; ++i) {
        const ushort* wb0i = wb + (size_t)i * 49152;
        const ushort* wb1i = wb + 245760 + (size_t)i * 16384;
        const ushort* wbsi = wb + 327680 + (size_t)i * 49152;
        k_segmax<<<12304, 256, 0, stream>>>((const uint*)net, starts, cnt, order, (uint*)seg,
                                            meanB + (i - 1) * 2048, wb0i, b0 + i * 128,
                                            wbsi, b1 + i * 128, rv0, rvS);
        const bool isLast = (i == NB - 1);
        float* mw = isLast ? nullptr : meanB + i * 2048;
        if (isLast && fused) {
            k_resblock<1, true><<<2048, 512, 0, stream>>>(
                nullptr, (const uint*)net, idx4, seg, rv0, rvS, nullptr, nullptr,
                nullptr, nullptr, wb0i, nullptr, wb1i, nullptr, wbsi, c3, nullptr,
                rank, wb + 573440, bc);
        } else {
            k_resblock<1, false><<<2048, 512, 0, stream>>>(
                nullptr, (const uint*)net, idx4, seg, rv0, rvS, nullptr, nullptr,
                nullptr, nullptr, wb0i, nullptr, wb1i, nullptr, wbsi, net, mw,
                nullptr, nullptr, nullptr);
        }
    }

    if (!fused) {
        k_fcc<<<2048, 256, 0, stream>>>((const uint*)net, rank, wb + 573440, bc, c3);
    }

    // --- fused segmented sum + transpose + divide, contiguous runs (32-cell tiles) ---
    k_segfin<<<6144, 256, 0, stream>>>((const uint*)c3, starts, cnt, out);
}

// Round 21
// 634.639 us; speedup vs baseline: 1.0212x; 1.0014x over previous
//
#include <hip/hip_runtime.h>

#define BT (16 * 8192)
#define NB 5
#define NCELL 65536  // B * RESO^2
typedef unsigned int uint;
typedef unsigned short ushort;
typedef __attribute__((ext_vector_type(8))) _Float16 half8;
typedef __attribute__((ext_vector_type(2))) __fp16 fp16x2;
typedef __attribute__((ext_vector_type(2))) _Float16 half2v;
typedef __attribute__((ext_vector_type(4))) float f32x4;

// NOTE (r5): aT lda dwords ≡ 4 mod 32 -> natural bank stagger; NO XOR swizzle.
// NOTE (r7/r9): resblock neither MFMA- nor VALU-bound. NOTE (r11): never alias a
// buffer read and written by the SAME kernel. NOTE (r17/r19): store-pattern surgery
// is neutral — working set is L3-resident; kernels are L2/L3-LATENCY bound on gathers.
// NOTE (r20): whole-pipeline plane-0-sorted-net reorder FAILED correctness (absmax
// 0.33, bug not locatable by inspection) — REVERTED to r19's known-good state.

// ---------- fp16 helpers ----------
__device__ __forceinline__ uint f2h2(float a, float b) {
    fp16x2 h = __builtin_amdgcn_cvt_pkrtz(a, b);
    return *(uint*)&h;
}
__device__ __forceinline__ float h2f_lo(uint u) { half2v h = *(half2v*)&u; return (float)h[0]; }
__device__ __forceinline__ float h2f_hi(uint u) { half2v h = *(half2v*)&u; return (float)h[1]; }
__device__ __forceinline__ uint pk_add(uint a, uint b) {
    uint d; asm("v_pk_add_f16 %0, %1, %2" : "=v"(d) : "v"(a), "v"(b)); return d;
}
__device__ __forceinline__ uint pk_max(uint a, uint b) {
    uint d; asm("v_pk_max_f16 %0, %1, %2" : "=v"(d) : "v"(a), "v"(b)); return d;
}

// relu on packed f16: single v_pk_max_f16 with +0 per dword
__device__ __forceinline__ half8 relu8(half8 a) {
    uint4 u = *(uint4*)&a;
    u.x = pk_max(u.x, 0u); u.y = pk_max(u.y, 0u);
    u.z = pk_max(u.z, 0u); u.w = pk_max(u.w, 0u);
    return *(half8*)&u;
}
__device__ __forceinline__ f32x4 bcast4(float x) { return (f32x4){x, x, x, x}; }
__device__ __forceinline__ f32x4 mfma16(half8 a, half8 b, f32x4 c) {
    return __builtin_amdgcn_mfma_f32_16x16x32_f16(a, b, c, 0, 0, 0);
}

// ---------- plane indices + histogram (fused; bitwise-identical idx math) ----------
__global__ void k_idx(const float* __restrict__ p, int* __restrict__ idx,
                      int4* __restrict__ idx4, int* __restrict__ cnt) {
    int r = blockIdx.x * 256 + threadIdx.x;
    if (r >= BT) return;
    float p0 = p[3 * r + 0], p1 = p[3 * r + 1], p2 = p[3 * r + 2];
    const float DEN = (float)(1.0 + 0.1 + 1e-3);
    const float HI  = (float)(1.0 - 1e-5);
    int b = r >> 13;  // T = 8192
    float x0 = fminf(fmaxf((p0 / 8.0f) / DEN + 0.5f, 0.0f), HI);
    float x1 = fminf(fmaxf((p1 / 8.0f) / DEN + 0.5f, 0.0f), HI);
    float x2 = fminf(fmaxf((p2 / 8.0f) / DEN + 0.5f, 0.0f), HI);
    int i0 = (int)(x0 * 64.0f);
    int i1 = (int)(x1 * 64.0f);
    int i2 = (int)(x2 * 64.0f);
    int base = b << 12;
    int exz = base + i0 + (i2 << 6);
    int exy = base + i0 + (i1 << 6);
    int eyz = base + i1 + (i2 << 6);
    idx[r] = exz; idx[BT + r] = exy; idx[2 * BT + r] = eyz;
    idx4[r] = make_int4(exz, exy, eyz, 0);
    atomicAdd(cnt + exz, 1);
    atomicAdd(cnt + NCELL + exy, 1);
    atomicAdd(cnt + 2 * NCELL + eyz, 1);
}

__global__ __launch_bounds__(1024) void k_scan(const int* __restrict__ cnt,
                                               int* __restrict__ starts,
                                               int* __restrict__ cursor) {
    __shared__ int sc[1024];
    int pl = blockIdx.x, t = threadIdx.x;
    const int* c = cnt + pl * NCELL;
    int base = t * 64;
    int s = 0;
    for (int i = 0; i < 64; ++i) s += c[base + i];
    sc[t] = s;
    __syncthreads();
    for (int off = 1; off < 1024; off <<= 1) {
        int v = (t >= off) ? sc[t - off] : 0;
        __syncthreads();
        sc[t] += v;
        __syncthreads();
    }
    int run = sc[t] - s;
    for (int i = 0; i < 64; ++i) {
        int cell = base + i;
        starts[pl * NCELL + cell] = run;
        cursor[pl * NCELL + cell] = run;
        run += c[cell];
    }
}

// order[pl][pos] = point id; rank[pl][r] = pos (inverse permutation)
__global__ void k_scatter_order(const int* __restrict__ idx, int* __restrict__ cursor,
                                int* __restrict__ order, int* __restrict__ rank) {
    int r = blockIdx.x * 256 + threadIdx.x;
    if (r >= BT) return;
    for (int pl = 0; pl < 3; ++pl) {
        int cell = idx[pl * BT + r];
        int pos = atomicAdd(cursor + pl * NCELL + cell, 1);
        order[pl * BT + pos] = r;
        rank[pl * BT + r] = pos;
    }
}

// ---------- weight convert + p-fold (fused; pfold = grid row y==16) ----------
__global__ void k_wconv(const float* __restrict__ W0, const float* __restrict__ W1,
                        const float* __restrict__ Ws, const float* __restrict__ Wc,
                        ushort* __restrict__ wb, const float* __restrict__ Wp,
                        const float* __restrict__ bp, const float* __restrict__ b1v,
                        float* __restrict__ M3, float* __restrict__ bps) {
    int mat = blockIdx.y;
    if (mat == 16) {  // p-fold: M3 = Wp @ Ws0 (3x128), bps = bp @ Ws0 + b1
        if (blockIdx.x != 0) return;
        int n = threadIdx.x;
        if (n >= 128) return;
        float s0 = 0.f, s1 = 0.f, s2 = 0.f, sb = b1v[n];
        for (int k = 0; k < 384; ++k) {
            float w = Ws[(size_t)k * 128 + n];
            s0 = fmaf(Wp[k], w, s0);
            s1 = fmaf(Wp[384 + k], w, s1);
            s2 = fmaf(Wp[768 + k], w, s2);
            sb = fmaf(bp[k], w, sb);
        }
        M3[n] = s0; M3[128 + n] = s1; M3[256 + n] = s2;
        bps[n] = sb;
        return;
    }
    int K = (mat < 5 || (mat >= 10 && mat < 15)) ? 384 : 128;
    int e = blockIdx.x * 256 + threadIdx.x;
    if (e >= K * 128) return;
    const float* src;
    size_t doff;
    if (mat < 5)       { src = W0 + (size_t)mat * 49152;        doff = (size_t)mat * 49152; }
    else if (mat < 10) { src = W1 + (size_t)(mat - 5) * 16384;  doff = 245760 + (size_t)(mat - 5) * 16384; }
    else if (mat < 15) { src = Ws + (size_t)(mat - 10) * 49152; doff = 327680 + (size_t)(mat - 10) * 49152; }
    else               { src = Wc;                              doff = 573440; }
    int ko = e & 31, n = (e >> 5) & 127, kt = e >> 12;
    wb[doff + e] = (ushort)f2h2(src[(size_t)(kt * 32 + ko) * 128 + n], 0.0f);
}

// ---------- segmented max: 4 cells per wave, batched gathers + meanvec tail ----------
__global__ __launch_bounds__(256) void k_segmax(const uint* __restrict__ netu,
                                                const int* __restrict__ starts,
                                                const int* __restrict__ cnt,
                                                const int* __restrict__ order,
                                                uint* __restrict__ segu,
                                                const float* __restrict__ meanPrev,
                                                const ushort* __restrict__ wb0,
                                                const float* __restrict__ b0v,
                                                const ushort* __restrict__ wbs,
                                                const float* __restrict__ b1v,
                                                float* __restrict__ rv0,
                                                float* __restrict__ rvS) {
    int t = threadIdx.x;
    if (blockIdx.x >= 12288) {
        __shared__ float ms[128];
        int b = blockIdx.x - 12288;
        if (t < 128) ms[t] = meanPrev[b * 128 + t];
        __syncthreads();
        if (t < 128) {
            float s0 = b0v[t], ss = b1v[t];
#pragma unroll 4
            for (int k = 0; k < 128; ++k) {
                float mv = ms[k];
                int kt = 8 + (k >> 5), ko = k & 31;
                float w0 = h2f_lo((uint)wb0[kt * 4096 + t * 32 + ko]);
                float ws = h2f_lo((uint)wbs[kt * 4096 + t * 32 + ko]);
                s0 = fmaf(fmaxf(mv, 0.0f), w0, s0);
                ss = fmaf(mv, ws, ss);
            }
            rv0[b * 128 + t] = s0;
            rvS[b * 128 + t] = ss;
        }
        return;
    }
    const int l = t & 63, wv = t >> 6;
    const int g0 = blockIdx.x * 16 + wv * 4;   // wave's first cell (4 consecutive)
    const int pl = g0 >> 16;                   // uniform per block (NCELL % 16 == 0)
    const int* ordp = order + pl * BT;

    int n[4], st[4];
#pragma unroll
    for (int c = 0; c < 4; ++c) { n[c] = cnt[g0 + c]; st[c] = starts[g0 + c]; }

    uint v[4][4];
#pragma unroll
    for (int c = 0; c < 4; ++c) {
        if (n[c] > 0) {
            const int* op = ordp + st[c];
            int nm1 = n[c] - 1;
#pragma unroll
            for (int k = 0; k < 4; ++k) {
                int kk = k < nm1 ? k : nm1;
                v[c][k] = netu[(size_t)op[kk] * 64 + l];
            }
        }
    }
#pragma unroll
    for (int c = 0; c < 4; ++c) {
        if (n[c] > 0) {
            uint m = pk_max(pk_max(v[c][0], v[c][1]), pk_max(v[c][2], v[c][3]));
            const int* op = ordp + st[c];
            int nm1 = n[c] - 1;
            for (int k = 4; k < n[c]; k += 4) {  // rare tail (n > 4)
                int k1 = k + 1 < nm1 ? k + 1 : nm1;
                int k2 = k + 2 < nm1 ? k + 2 : nm1;
                int k3 = k + 3 < nm1 ? k + 3 : nm1;
                uint a = netu[(size_t)op[k] * 64 + l];
                uint b = netu[(size_t)op[k1] * 64 + l];
                uint cc = netu[(size_t)op[k2] * 64 + l];
                uint d = netu[(size_t)op[k3] * 64 + l];
                m = pk_max(m, pk_max(pk_max(a, b), pk_max(cc, d)));
            }
            segu[(size_t)(g0 + c) * 64 + l] = m;
        }
    }
}

// ---------- fused resblock (f16 MFMA, padded LDS, rank-1 mean, rank-3 p-fold) ----------
// LAST: fc_c fused — Wc pass over hT, then ROW-STAGED c3 writes (full 256B rows).
template <int MODE, bool LAST>
__global__ __launch_bounds__(512, MODE == 0 ? 6 : 8) void k_resblock(
    const float* __restrict__ p, const uint* __restrict__ netu,
    const int4* __restrict__ idx4, const ushort* __restrict__ seg,
    const float* __restrict__ rv0, const float* __restrict__ rvS,
    const float* __restrict__ Wp, const float* __restrict__ bp,
    const float* __restrict__ M3, const float* __restrict__ bps,
    const ushort* __restrict__ wb0, const float* __restrict__ b0v,
    const ushort* __restrict__ wb1, const float* __restrict__ b1v,
    const ushort* __restrict__ wbs,
    ushort* __restrict__ out, float* __restrict__ meanW,
    const int* __restrict__ rank, const ushort* __restrict__ wbc,
    const float* __restrict__ bcv) {
    constexpr int LDA = (MODE == 0) ? 392 : 264;  // ushort stride; dwords ≡ 4 mod 32
    constexpr int NKT = (MODE == 0) ? 12 : 8;
    __shared__ __align__(16) ushort aT[64 * LDA];
    __shared__ float pS[MODE == 0 ? 192 : 1];  // MODE0: 64 rows x 3 f32
    __shared__ int rkS[LAST ? 192 : 1];
    ushort* hT = aT;  // alias: hidden tile; c-input staging; c-output staging (LAST)
    const int t = threadIdx.x;  // 0..511
    const int rowBase = blockIdx.x * 64;
    const int bb = rowBase >> 13;

    if constexpr (LAST) {
        if (t < 192) rkS[t] = rank[(t >> 6) * BT + rowBase + (t & 63)];
    }

    if constexpr (MODE == 0) {
        if (t < 192) pS[t] = p[(size_t)rowBase * 3 + t];
        __syncthreads();
        for (int f = t; f < 3072; f += 512) {
            int row = f / 48, g = f - row * 48;
            float p0 = pS[row * 3 + 0], p1 = pS[row * 3 + 1], p2 = pS[row * 3 + 2];
            int k0 = g * 8;
            uint d[4];
#pragma unroll
            for (int w = 0; w < 4; ++w) {
                int k = k0 + 2 * w;
                float v0 = bp[k]     + p0 * Wp[k]     + p1 * Wp[384 + k]     + p2 * Wp[768 + k];
                float v1 = bp[k + 1] + p0 * Wp[k + 1] + p1 * Wp[384 + k + 1] + p2 * Wp[768 + k + 1];
                d[w] = f2h2(v0, v1);
            }
            *(uint4*)(aT + row * LDA + k0) = make_uint4(d[0], d[1], d[2], d[3]);
        }
    } else {
        const uint4* nsrc = (const uint4*)netu;
#pragma unroll
        for (int i = 0; i < 2; ++i) {  // net -> cols [0,128)
            int f = t + 512 * i;
            int row = f >> 4, cu = f & 15;
            *(uint4*)(aT + row * LDA + cu * 8) = nsrc[(size_t)(rowBase + row) * 16 + cu];
        }
#pragma unroll
        for (int i = 0; i < 2; ++i) {  // pooled (3-plane packed-f16 sum) -> cols [128,256)
            int f = t + 512 * i;
            int row = f >> 4, grp = f & 15;
            int4 cc = idx4[rowBase + row];
            uint4 A = *(const uint4*)(seg + ((size_t)cc.x) * 128 + grp * 8);
            uint4 B = *(const uint4*)(seg + ((size_t)NCELL + cc.y) * 128 + grp * 8);
            uint4 C = *(const uint4*)(seg + ((size_t)2 * NCELL + cc.z) * 128 + grp * 8);
            uint4 d;
            d.x = pk_add(pk_add(A.x, B.x), C.x);
            d.y = pk_add(pk_add(A.y, B.y), C.y);
            d.z = pk_add(pk_add(A.z, B.z), C.z);
            d.w = pk_add(pk_add(A.w, B.w), C.w);
            *(uint4*)(aT + row * LDA + 128 + grp * 8) = d;
        }
    }
    __syncthreads();

    const int l = t & 63, wid = t >> 6;  // wid 0..7
    const int n0 = wid * 16;
    const int lm = l & 15, lg = l >> 4;
    const ushort* w0 = wb0 + n0 * 32;
    const ushort* w1 = wb1 + n0 * 32;
    const ushort* ws = wbs + n0 * 32;

    f32x4 acc0[4], accS[4];
    {
        float bi;
        if constexpr (MODE == 0) bi = b0v[n0 + lm];
        else                     bi = rv0[bb * 128 + n0 + lm];
#pragma unroll
        for (int im = 0; im < 4; ++im) acc0[im] = bcast4(bi);
    }
    if constexpr (MODE == 1) {
        float si = rvS[bb * 128 + n0 + lm];
#pragma unroll
        for (int im = 0; im < 4; ++im) accS[im] = bcast4(si);
    }
#pragma unroll
    for (int kt = 0; kt < NKT; ++kt) {
        half8 b0 = *(const half8*)(w0 + kt * 4096 + lm * 32 + lg * 8);
        half8 bs;
        if constexpr (MODE == 1) bs = *(const half8*)(ws + kt * 4096 + lm * 32 + lg * 8);
#pragma unroll
        for (int im = 0; im < 4; ++im) {
            half8 a = *(const half8*)(aT + (im * 16 + lm) * LDA + kt * 32 + lg * 8);
            acc0[im] = mfma16(relu8(a), b0, acc0[im]);
            if constexpr (MODE == 1) accS[im] = mfma16(a, bs, accS[im]);
        }
    }
    if constexpr (MODE == 0) {
        int col = n0 + lm;
        float m0 = M3[col], m1 = M3[128 + col], m2 = M3[256 + col], bb2 = bps[col];
#pragma unroll
        for (int im = 0; im < 4; ++im)
#pragma unroll
            for (int j = 0; j < 4; ++j) {
                int row = im * 16 + lg * 4 + j;
                accS[im][j] = fmaf(pS[row * 3 + 0], m0,
                              fmaf(pS[row * 3 + 1], m1,
                              fmaf(pS[row * 3 + 2], m2, bb2)));
            }
    }
    __syncthreads();  // all waves done READING aT (and pS) before hT overwrites

    // h = relu(acc0) -> hT (aliases aT; stride 136, dwords 68 ≡ 4 mod 32)
#pragma unroll
    for (int im = 0; im < 4; ++im)
#pragma unroll
        for (int j = 0; j < 4; ++j) {
            int row = im * 16 + lg * 4 + j;
            hT[row * 136 + n0 + lm] = (ushort)f2h2(fmaxf(acc0[im][j], 0.0f), 0.0f);
        }
    __syncthreads();

    // accS += h @ W1
#pragma unroll
    for (int kt = 0; kt < 4; ++kt) {
        half8 b = *(const half8*)(w1 + kt * 4096 + lm * 32 + lg * 8);
#pragma unroll
        for (int im = 0; im < 4; ++im) {
            half8 a = *(const half8*)(hT + (im * 16 + lm) * 136 + kt * 32 + lg * 8);
            accS[im] = mfma16(a, b, accS[im]);
        }
    }

    if constexpr (!LAST) {
        // store out (f16) — contiguous dest: scalar stores combine fine in L2 (r17)
#pragma unroll
        for (int im = 0; im < 4; ++im)
#pragma unroll
            for (int j = 0; j < 4; ++j) {
                int row = rowBase + im * 16 + lg * 4 + j;
                out[(size_t)row * 128 + n0 + lm] = (ushort)f2h2(accS[im][j], 0.0f);
            }
        // fused batch-mean (input to next block's meanvec); cols disjoint across waves
        if (meanW) {
            float s = 0.0f;
#pragma unroll
            for (int im = 0; im < 4; ++im)
#pragma unroll
                for (int j = 0; j < 4; ++j) s += accS[im][j];
            s += __shfl_xor(s, 16);
            s += __shfl_xor(s, 32);
            if (l < 16) atomicAdd(meanW + bb * 128 + n0 + l, s * (1.0f / 8192.0f));
        }
    } else {
        // fused fc_c: c_in = f16(accS) -> hT, c = c_in @ Wc + bc, then ROW-STAGED writes
        __syncthreads();  // all waves done READING hT (W1 pass)
#pragma unroll
        for (int im = 0; im < 4; ++im)
#pragma unroll
            for (int j = 0; j < 4; ++j) {
                int row = im * 16 + lg * 4 + j;
                hT[row * 136 + n0 + lm] = (ushort)f2h2(accS[im][j], 0.0f);
            }
        __syncthreads();
        f32x4 accC[4];
        {
            float ci = bcv[n0 + lm];
#pragma unroll
            for (int im = 0; im < 4; ++im) accC[im] = bcast4(ci);
        }
        const ushort* wc = wbc + n0 * 32;
#pragma unroll
        for (int kt = 0; kt < 4; ++kt) {
            half8 b = *(const half8*)(wc + kt * 4096 + lm * 32 + lg * 8);
#pragma unroll
            for (int im = 0; im < 4; ++im) {
                half8 a = *(const half8*)(hT + (im * 16 + lm) * 136 + kt * 32 + lg * 8);
                accC[im] = mfma16(a, b, accC[im]);
            }
        }
        __syncthreads();  // all waves done READING hT (Wc pass)
        // stage c-output into hT
#pragma unroll
        for (int im = 0; im < 4; ++im)
#pragma unroll
            for (int j = 0; j < 4; ++j) {
                int row = im * 16 + lg * 4 + j;
                hT[row * 136 + n0 + lm] = (ushort)f2h2(accC[im][j], 0.0f);
            }
        __syncthreads();
        // write 3 copies: 16 consecutive lanes emit one full 256B row per copy
#pragma unroll
        for (int i = 0; i < 2; ++i) {
            int f = t + 512 * i;
            int row = f >> 4, cu = f & 15;
            uint4 v = *(const uint4*)(hT + row * 136 + cu * 8);
            *(uint4*)(out + (size_t)rkS[row] * 128 + cu * 8) = v;
            *(uint4*)(out + ((size_t)BT + rkS[64 + row]) * 128 + cu * 8) = v;
            *(uint4*)(out + ((size_t)2 * BT + rkS[128 + row]) * 128 + cu * 8) = v;
        }
    }
}

// ---------- GEMM helper (k_fcc fallback only) ----------
__device__ __forceinline__ void mfma_gemm3(const ushort* __restrict__ aLDS, int lda, int nk,
                                           const ushort* __restrict__ wb, int lm, int lg,
                                           f32x4 acc[4][2]) {
    for (int kt = 0; kt < nk; ++kt) {
        half8 b0 = *(const half8*)(wb + kt * 4096 + lm * 32 + lg * 8);
        half8 b1 = *(const half8*)(wb + kt * 4096 + (16 + lm) * 32 + lg * 8);
#pragma unroll
        for (int im = 0; im < 4; ++im) {
            half8 a = *(const half8*)(aLDS + (im * 16 + lm) * lda + kt * 32 + lg * 8);
            acc[im][0] = mfma16(a, b0, acc[im][0]);
            acc[im][1] = mfma16(a, b1, acc[im][1]);
        }
    }
}

// ---------- fallback final projection (only when ws too small for fused path) ----------
__global__ __launch_bounds__(256, 2) void k_fcc(const uint* __restrict__ netu,
                                                const int* __restrict__ rank,
                                                const ushort* __restrict__ wbc,
                                                const float* __restrict__ bc,
                                                ushort* __restrict__ c3) {
    __shared__ __align__(16) ushort aT[64 * 136];
    __shared__ int rkS[3][64];
    const int t = threadIdx.x;
    const int rowBase = blockIdx.x * 64;
    if (t < 192) {
        int pl = t >> 6, rr = t & 63;
        rkS[pl][rr] = rank[pl * BT + rowBase + rr];
    }
    const uint4* nsrc = (const uint4*)netu;
#pragma unroll
    for (int i = 0; i < 4; ++i) {
        int u = t + 256 * i;
        int row = u >> 4, cu = u & 15;
        *(uint4*)(aT + row * 136 + cu * 8) = nsrc[(size_t)(rowBase + row) * 16 + cu];
    }
    __syncthreads();
    const int l = t & 63, wid = t >> 6;
    const int n0 = wid * 32;
    const int lm = l & 15, lg = l >> 4;
    f32x4 acc[4][2];
    {
        float ci0 = bc[n0 + lm], ci1 = bc[n0 + 16 + lm];
#pragma unroll
        for (int im = 0; im < 4; ++im) { acc[im][0] = bcast4(ci0); acc[im][1] = bcast4(ci1); }
    }
    mfma_gemm3(aT, 136, 4, wbc + n0 * 32, lm, lg, acc);
#pragma unroll
    for (int im = 0; im < 4; ++im)
#pragma unroll
        for (int ic = 0; ic < 2; ++ic)
#pragma unroll
            for (int j = 0; j < 4; ++j) {
                int row = im * 16 + lg * 4 + j;
                int col = n0 + ic * 16 + lm;
                ushort v = (ushort)f2h2(acc[im][ic][j], 0.0f);
                c3[(size_t)rkS[0][row] * 128 + col] = v;
                c3[((size_t)BT + rkS[1][row]) * 128 + col] = v;
                c3[((size_t)2 * BT + rkS[2][row]) * 128 + col] = v;
            }
}

// ---------- fused segmented-sum + transpose + divide over CONTIGUOUS runs ----------
// 32 cells/block (16.6 KB LDS -> 8 blocks/CU = 100% occupancy ceiling); 6144 blocks.
__global__ __launch_bounds__(256) void k_segfin(const uint* __restrict__ c3,
                                                const int* __restrict__ starts,
                                                const int* __restrict__ cnt,
                                                float* __restrict__ out) {
    __shared__ float tile[32 * 130];  // stride 130 dwords ≡ 2 mod 32 (2-way max)
    const int t = threadIdx.x;
    const int w = t >> 6, l = t & 63;
    const int bx = blockIdx.x;
    const int pl = bx >> 11;          // 2048 blocks per plane
    const int rem = bx & 2047;
    const int b = rem >> 7;
    const int cl0 = (rem & 127) << 5;  // 32 cells per block
    const int gbase = pl * NCELL + (b << 12) + cl0;

    for (int i = 0; i < 8; ++i) {
        int cellLocal = w * 8 + i;
        int g = gbase + cellLocal;
        int n = cnt[g];
        float s0 = 0.f, s1 = 0.f;
        if (n > 0) {
            size_t rowb = (size_t)pl * BT + starts[g];  // contiguous run
            int j = 0;
            for (; j + 4 <= n; j += 4) {
                uint a = c3[(rowb + j) * 64 + l];
                uint bq = c3[(rowb + j + 1) * 64 + l];
                uint c = c3[(rowb + j + 2) * 64 + l];
                uint d = c3[(rowb + j + 3) * 64 + l];
                s0 += (h2f_lo(a) + h2f_lo(bq)) + (h2f_lo(c) + h2f_lo(d));
                s1 += (h2f_hi(a) + h2f_hi(bq)) + (h2f_hi(c) + h2f_hi(d));
            }
            int rm = n - j;
            if (rm > 0) {
                uint a = c3[(rowb + j) * 64 + l];
                uint bq = (rm > 1) ? c3[(rowb + j + 1) * 64 + l] : 0u;
                uint c = (rm > 2) ? c3[(rowb + j + 2) * 64 + l] : 0u;
                s0 += h2f_lo(a) + (h2f_lo(bq) + h2f_lo(c));
                s1 += h2f_hi(a) + (h2f_hi(bq) + h2f_hi(c));
            }
        }
        *(float2*)(tile + cellLocal * 130 + 2 * l) = make_float2(s0, s1);
    }
    __syncthreads();

    // write: thread t -> cell (t & 31), channels [(t>>5)*16, +16)
    const int cell = t & 31;
    const int ch0 = (t >> 5) * 16;
    int cn = cnt[gbase + cell];
    float inv = cn > 0 ? 1.0f / (float)cn : 0.0f;
    size_t obase = (((size_t)((pl * 16 + b) * 128)) << 12) + cl0 + cell;
#pragma unroll
    for (int j = 0; j < 16; ++j) {
        int ch = ch0 + j;
        out[obase + ((size_t)ch << 12)] = tile[cell * 130 + ch] * inv;
    }
}

// ---------- launch ----------
extern "C" void kernel_launch(void* const* d_in, const int* in_sizes, int n_in,
                              void* d_out, int out_size, void* d_ws, size_t ws_size,
                              hipStream_t stream) {
    const float* p  = (const float*)d_in[0];
    const float* Wp = (const float*)d_in[1];
    const float* bp = (const float*)d_in[2];
    const float* W0 = (const float*)d_in[3];
    const float* b0 = (const float*)d_in[4];
    const float* W1 = (const float*)d_in[5];
    const float* b1 = (const float*)d_in[6];
    const float* Ws = (const float*)d_in[7];
    const float* Wc = (const float*)d_in[8];
    const float* bc = (const float*)d_in[9];
    float* out = (float*)d_out;

    // Fused path needs seg separate from c3 (LAST resblock reads seg + writes c3).
    const size_t NEED_FUSED = 196u * 1024 * 1024;  // ~196 MB with margin
    const bool fused = ws_size >= NEED_FUSED;

    ushort* c3  = (ushort*)d_ws;                          // 96 MB
    ushort* seg = fused ? (c3 + 50331648) : c3;           // separate 48 MB or alias
    ushort* net = seg + 25165824;                         // 32 MB
    ushort* wb  = net + 16777216;
    int*    idx    = (int*)(wb + 589824);
    int*    order  = idx + 393216;
    int*    rank   = order + 393216;
    int*    cnt    = rank + 393216;
    int*    starts = cnt + 196608;
    int*    cursor = starts + 196608;
    int4*   idx4   = (int4*)(cursor + 196608);
    float*  meanB  = (float*)(idx4 + 131072);
    float*  rv0    = meanB + 4 * 2048;
    float*  rvS    = rv0 + 2048;
    float*  M3     = rvS + 2048;
    float*  bps    = M3 + 384;

    // --- sort points by cell (loop-invariant) + weight convert + p-fold ---
    (void)hipMemsetAsync(cnt, 0, 3 * NCELL * 4, stream);
    k_idx<<<512, 256, 0, stream>>>(p, idx, idx4, cnt);           // idx + histogram fused
    k_scan<<<3, 1024, 0, stream>>>(cnt, starts, cursor);
    k_scatter_order<<<512, 256, 0, stream>>>(idx, cursor, order, rank);
    k_wconv<<<dim3(192, 17), 256, 0, stream>>>(W0, W1, Ws, Wc, wb, Wp, bp, b1, M3, bps);
    (void)hipMemsetAsync(meanB, 0, 4 * 2048 * 4, stream);

    // --- block 0 (fc_pos fused, shortcut folded), writes mean slot 0 ---
    k_resblock<0, false><<<2048, 512, 0, stream>>>(
        p, nullptr, nullptr, nullptr, nullptr, nullptr, Wp, bp, M3, bps,
        wb, b0, wb + 245760, b1, wb + 327680, net, meanB,
        nullptr, nullptr, nullptr);

    for (int i = 1; i < NB; ++i) {
        const ushort* wb0i = wb + (size_t)i * 49152;
        const ushort* wb1i = wb + 245760 + (size_t)i * 16384;
        const ushort* wbsi = wb + 327680 + (size_t)i * 49152;
        k_segmax<<<12304, 256, 0, stream>>>((const uint*)net, starts, cnt, order, (uint*)seg,
                                            meanB + (i - 1) * 2048, wb0i, b0 + i * 128,
                                            wbsi, b1 + i * 128, rv0, rvS);
        const bool isLast = (i == NB - 1);
        float* mw = isLast ? nullptr : meanB + i * 2048;
        if (isLast && fused) {
            k_resblock<1, true><<<2048, 512, 0, stream>>>(
                nullptr, (const uint*)net, idx4, seg, rv0, rvS, nullptr, nullptr,
                nullptr, nullptr, wb0i, nullptr, wb1i, nullptr, wbsi, c3, nullptr,
                rank, wb + 573440, bc);
        } else {
            k_resblock<1, false><<<2048, 512, 0, stream>>>(
                nullptr, (const uint*)net, idx4, seg, rv0, rvS, nullptr, nullptr,
                nullptr, nullptr, wb0i, nullptr, wb1i, nullptr, wbsi, net, mw,
                nullptr, nullptr, nullptr);
        }
    }

    if (!fused) {
        k_fcc<<<2048, 256, 0, stream>>>((const uint*)net, rank, wb + 573440, bc, c3);
    }

    // --- fused segmented sum + transpose + divide, contiguous runs (32-cell tiles) ---
    k_segfin<<<6144, 256, 0, stream>>>((const uint*)c3, starts, cnt, out);
}